// Round 8
// baseline (219.885 us; speedup 1.0000x reference)
//
#include <hip/hip_runtime.h>
#include <hip/hip_bf16.h>

typedef short s16x4 __attribute__((ext_vector_type(4)));
typedef short s16x8 __attribute__((ext_vector_type(8)));
typedef float f32x4 __attribute__((ext_vector_type(4)));
typedef float f32x16 __attribute__((ext_vector_type(16)));

#define NB 2
#define NSEQ 2048
#define NHID 896
#define NHQ 14
#define NHKV 2
#define HD 64
#define NROW (NB*NSEQ)     // 4096
#define NCAT 2048          // 896 Q | 128 K | 128 V | 896 gate
#define PS 40              // padded LDS row stride in shorts (80B, 16B-aligned)
#define QSC 0.18033688011112042f   // (1/8) * log2(e), folded into Q at projection

__device__ __forceinline__ float bf2f(unsigned short s){
  union { float f; unsigned u; } v; v.u = ((unsigned)s) << 16; return v.f;
}
__device__ __forceinline__ short f2bf(float f){
  union { float f; unsigned u; } v; v.f = f;
  unsigned u = v.u + 0x7fffu + ((v.u >> 16) & 1u);
  return (short)(u >> 16);
}

// ---------------- packing kernels ----------------

__global__ void pack_x_kernel(const float* __restrict__ x, short* __restrict__ xb, int n){
  int i = blockIdx.x*256 + threadIdx.x;
  if(i < n) xb[i] = f2bf(x[i]);
}

__global__ void pack_wcat_kernel(const float* __restrict__ Wq, const float* __restrict__ Wk,
                                 const float* __restrict__ Wv, const float* __restrict__ Wg,
                                 short* __restrict__ WcatT){
  int t = blockIdx.x*256 + threadIdx.x;
  if(t >= NCAT*NHID) return;
  int k = t % NHID, c = t / NHID;
  float v;
  if(c < 896)       v = Wq[k*896 + c];
  else if(c < 1024) v = Wk[k*128 + (c-896)];
  else if(c < 1152) v = Wv[k*128 + (c-1024)];
  else              v = Wg[k*896 + (c-1152)];
  WcatT[t] = f2bf(v);
}

__global__ void pack_wo_kernel(const float* __restrict__ Wo, short* __restrict__ WoT){
  int t = blockIdx.x*256 + threadIdx.x;
  if(t >= NHID*NHID) return;
  int k = t % NHID, c = t / NHID;
  WoT[t] = f2bf(Wo[k*896 + c]);
}

__global__ void rope_table_kernel(const int* __restrict__ pos, float* __restrict__ ct,
                                  float* __restrict__ st){
  int t = blockIdx.x*256 + threadIdx.x;
  if(t >= NROW*32) return;
  int i = t & 31, rn = t >> 5;
  float p = (float)pos[rn];
  float inv = powf(1.0e6f, -(float)i * (1.0f/32.0f));
  float a = p * inv;
  ct[t] = cosf(a);
  st[t] = sinf(a);
}

// V [bh][n][d] -> VbT [bh][d][n]  (LDS tiled transpose, bf16)
__global__ __launch_bounds__(256) void transpose_v_kernel(const short* __restrict__ Vb,
                                                          short* __restrict__ VbT){
  __shared__ short t[64][66];
  int bh = blockIdx.y;
  int n0 = blockIdx.x * 64;
  int tid = threadIdx.x;
  #pragma unroll
  for(int it=0; it<2; ++it){
    int idx = it*256 + tid;
    int r = idx >> 3, c0 = (idx & 7)*8;
    s16x8 v = *(const s16x8*)(Vb + ((long)bh*NSEQ + n0 + r)*HD + c0);
    #pragma unroll
    for(int e=0;e<8;e++) t[r][c0+e] = v[e];
  }
  __syncthreads();
  #pragma unroll
  for(int it=0; it<2; ++it){
    int idx = it*256 + tid;
    int d = idx >> 3, k0 = (idx & 7)*8;
    s16x8 o;
    #pragma unroll
    for(int e=0;e<8;e++) o[e] = t[k0+e][d];
    *(s16x8*)(VbT + ((long)bh*HD + d)*NSEQ + n0 + k0) = o;
  }
}

// ---------------- GEMM (bf16 MFMA, reg-staged LDS double-buffer) ----------------
// EPI=0: QKVG epilogue (Q pre-scaled by QSC), EPI=1: plain f32 out
// NOTE: every loop touching acc[][] MUST be #pragma unroll'd (rule #20).

template<int EPI>
__global__ __launch_bounds__(256)
void gemm_kernel(const short* __restrict__ A, const short* __restrict__ Bt,
                 int Ncols, int K,
                 const float* __restrict__ bq, const float* __restrict__ bk,
                 const float* __restrict__ bv,
                 const float* __restrict__ ct, const float* __restrict__ st,
                 short* __restrict__ Qb, short* __restrict__ Kb, short* __restrict__ Vb,
                 short* __restrict__ gateb, float* __restrict__ outp)
{
  __shared__ short As[2][128*PS];
  __shared__ short Bs[2][128*PS];

  int tid = threadIdx.x;
  int w = tid >> 6, l = tid & 63;
  int wm = w >> 1, wn = w & 1;
  int row0 = blockIdx.y*128;
  int col0 = blockIdx.x*128;
  int lo = l & 15, hi = l >> 4;

  const short* A0 = A  + (long)row0*K;
  const short* B0 = Bt + (long)col0*K;

  f32x4 acc[4][4];
  #pragma unroll
  for(int mi=0;mi<4;mi++)
    #pragma unroll
    for(int ni=0;ni<4;ni++) acc[mi][ni] = (f32x4){0.f,0.f,0.f,0.f};

  int srow = tid >> 2;
  int scol = (tid & 3)*8;

  s16x8 ra[2], rb[2];
  auto gload = [&](int k0){
    #pragma unroll
    for(int i=0;i<2;i++){
      int row = i*64 + srow;
      ra[i] = *(const s16x8*)(A0 + (long)row*K + k0 + scol);
      rb[i] = *(const s16x8*)(B0 + (long)row*K + k0 + scol);
    }
  };
  auto swrite = [&](int buf){
    #pragma unroll
    for(int i=0;i<2;i++){
      int row = i*64 + srow;
      *(s16x8*)&As[buf][row*PS + scol] = ra[i];
      *(s16x8*)&Bs[buf][row*PS + scol] = rb[i];
    }
  };

  gload(0);
  swrite(0);

  int NIT = K >> 5;
  int cur = 0;
  for(int it=0; it<NIT; ++it){
    __syncthreads();
    if(it+1 < NIT) gload((it+1)*32);

    s16x8 af[4], bf[4];
    #pragma unroll
    for(int mi=0;mi<4;mi++) af[mi] = *(const s16x8*)&As[cur][(wm*64 + 16*mi + lo)*PS + 8*hi];
    #pragma unroll
    for(int ni=0;ni<4;ni++) bf[ni] = *(const s16x8*)&Bs[cur][(wn*64 + 16*ni + lo)*PS + 8*hi];
    #pragma unroll
    for(int mi=0;mi<4;mi++)
      #pragma unroll
      for(int ni=0;ni<4;ni++)
        acc[mi][ni] = __builtin_amdgcn_mfma_f32_16x16x32_bf16(af[mi], bf[ni], acc[mi][ni], 0,0,0);

    if(it+1 < NIT) swrite(cur^1);
    cur ^= 1;
  }

  if(EPI == 1){
    #pragma unroll
    for(int mi=0;mi<4;mi++)
      #pragma unroll
      for(int ni=0;ni<4;ni++)
        #pragma unroll
        for(int rg=0;rg<4;rg++){
          int r = row0 + wm*64 + 16*mi + 4*hi + rg;
          int c = col0 + wn*64 + lo + 16*ni;
          outp[(long)r*Ncols + c] = acc[mi][ni][rg];
        }
  } else {
    int wcol0 = col0 + wn*64;
    int region = (wcol0 < 896) ? 0 : (wcol0 < 1024) ? 1 : (wcol0 < 1152) ? 2 : 3;
    #pragma unroll
    for(int mi=0;mi<4;mi++){
      #pragma unroll
      for(int rg=0;rg<4;rg++){
        int r = row0 + wm*64 + 16*mi + 4*hi + rg;
        int b = r >> 11, n = r & 2047;
        if(region <= 1){
          #pragma unroll
          for(int ni=0;ni<2;ni++){
            int c  = wcol0 + lo + 16*ni;
            int cb = (region==0) ? c : (c-896);
            int hh = cb >> 6, dlo = cb & 63;
            float bl = (region==0) ? bq[c]    : bk[cb];
            float bh = (region==0) ? bq[c+32] : bk[cb+32];
            float ylo = acc[mi][ni  ][rg] + bl;
            float yhi = acc[mi][ni+2][rg] + bh;
            float cs = ct[r*32 + dlo];
            float sn = st[r*32 + dlo];
            float olo = ylo*cs - yhi*sn;
            float ohi = yhi*cs + ylo*sn;
            if(region==0){
              long base = ((long)(b*NHQ + hh)*NSEQ + n)*HD;
              Qb[base + dlo]      = f2bf(olo*QSC);
              Qb[base + dlo + 32] = f2bf(ohi*QSC);
            } else {
              long base = ((long)(b*NHKV + hh)*NSEQ + n)*HD;
              Kb[base + dlo]      = f2bf(olo);
              Kb[base + dlo + 32] = f2bf(ohi);
            }
          }
        } else if(region == 2){
          #pragma unroll
          for(int ni=0;ni<4;ni++){
            int c = wcol0 + lo + 16*ni;
            int cv = c - 1024;
            int hh = cv >> 6, d = cv & 63;
            float y = acc[mi][ni][rg] + bv[cv];
            Vb[((long)(b*NHKV + hh)*NSEQ + n)*HD + d] = f2bf(y);
          }
        } else {
          #pragma unroll
          for(int ni=0;ni<4;ni++){
            int c = wcol0 + lo + 16*ni;
            int cg = c - 1152;
            float y = acc[mi][ni][rg];
            gateb[(long)r*NHID + cg] = f2bf(1.0f/(1.0f + __expf(-y)));
          }
        }
      }
    }
  }
}

// ---------------- split-K flash attention, 7 GQA heads per block ----------------
// 7 waves/block (448 thr), wave w = q-head hg; all waves share the same K/V
// chunk -> L1 reuse + high waves/CU. Per-wave body identical to the verified
// R7 stream (zero LDS, zero barriers). Chunk map & combine unchanged.

__global__ __launch_bounds__(448)
void attn3_kernel(const short* __restrict__ Qb, const short* __restrict__ Kb,
                  const short* __restrict__ VbT, const short* __restrict__ gateb,
                  short* __restrict__ Og, float* __restrict__ Pbuf)
{
  int tid = threadIdx.x;
  int q5 = tid & 31, h = (tid >> 5) & 1;
  int hg = tid >> 6;              // wave id = head-in-group 0..6

  int s = blockIdx.x;             // 0..159 chunk slot
  int kvb = blockIdx.y;           // 0..3 = (b,kv)
  int b = kvb >> 1, kv = kvb & 1;
  int hq = kv*7 + hg;
  int head = kvb*7 + hg;          // Pbuf head index (matches combine decode)

  int t, ci, nc;
  if(s < 16){ t = s; ci = 0; nc = 1; }
  else if(s < 48){ int r = s-16; t = 16 + (r>>1); ci = r & 1; nc = 2; }
  else if(s < 96){ int r = s-48; t = 32 + r/3; ci = r - (r/3)*3; nc = 3; }
  else { int r = s-96; t = 48 + (r>>2); ci = r & 3; nc = 4; }

  int qg = t*32 + q5;
  int jcausal = (t*32 + 31) >> 6;           // diagonal 64-key group; in last chunk
  int j0 = ci*8;
  int j1 = (ci == nc-1) ? jcausal : (j0 + 7);

  const short* qrow = Qb + ((long)(b*NHQ + hq)*NSEQ + t*32 + q5)*HD;
  s16x8 qf[4];
  #pragma unroll
  for(int ks=0; ks<4; ++ks) qf[ks] = *(const s16x8*)(qrow + 16*ks + 8*h);

  const short* kbase = Kb  + (long)(b*NHKV + kv)*NSEQ*HD;
  const short* vbase = VbT + (long)(b*NHKV + kv)*HD*NSEQ;

  f32x16 oT[2];
  #pragma unroll
  for(int mt=0; mt<2; ++mt)
    #pragma unroll
    for(int rg=0; rg<16; ++rg) oT[mt][rg] = 0.f;
  float m = -__builtin_inff(), lsum = 0.f;

  // preload K group j0: A-frag rows = key, k = d
  s16x8 kf[2][4];
  #pragma unroll
  for(int kt=0; kt<2; ++kt)
    #pragma unroll
    for(int ks=0; ks<4; ++ks)
      kf[kt][ks] = *(const s16x8*)(kbase + (long)(j0*64 + kt*32 + q5)*HD + 16*ks + 8*h);

  for(int j=j0; j<=j1; ++j){
    // V A-frags (permuted key order): elements e<4 at key 16s+4h+e, e>=4 at +8
    union V8 { s16x8 v8; s16x4 v4[2]; } vf[2][4];
    #pragma unroll
    for(int mt=0; mt<2; ++mt)
      #pragma unroll
      for(int ss=0; ss<4; ++ss){
        const short* vp = vbase + (long)(mt*32 + q5)*NSEQ + j*64 + 16*ss + 4*h;
        vf[mt][ss].v4[0] = *(const s16x4*)(vp);
        vf[mt][ss].v4[1] = *(const s16x4*)(vp + 8);
      }

    // S^T = K * Q^T (softmax scale pre-folded into Q, log2 domain)
    f32x16 s2[2];
    #pragma unroll
    for(int kt=0; kt<2; ++kt)
      #pragma unroll
      for(int rg=0; rg<16; ++rg) s2[kt][rg] = 0.f;
    #pragma unroll
    for(int kt=0; kt<2; ++kt)
      #pragma unroll
      for(int ks=0; ks<4; ++ks)
        s2[kt] = __builtin_amdgcn_mfma_f32_32x32x16_bf16(kf[kt][ks], qf[ks], s2[kt], 0,0,0);

    // prefetch next K group while softmax+PV run
    int jn = (j < j1) ? j+1 : j;
    s16x8 kn[2][4];
    #pragma unroll
    for(int kt=0; kt<2; ++kt)
      #pragma unroll
      for(int ks=0; ks<4; ++ks)
        kn[kt][ks] = *(const s16x8*)(kbase + (long)(jn*64 + kt*32 + q5)*HD + 16*ks + 8*h);

    // causal mask (diagonal group only). key row = (rg&3)+8*(rg>>2)+4h
    if(j == jcausal){
      #pragma unroll
      for(int kt=0; kt<2; ++kt)
        #pragma unroll
        for(int rg=0; rg<16; ++rg){
          int kl = j*64 + kt*32 + (rg&3) + 8*(rg>>2) + 4*h;
          if(kl > qg) s2[kt][rg] = -__builtin_inff();
        }
    }

    // row-max: in-lane tree + 1 shuffle across h
    float mA[8];
    #pragma unroll
    for(int w8=0; w8<8; ++w8)
      mA[w8] = fmaxf(fmaxf(s2[0][w8], s2[0][w8+8]), fmaxf(s2[1][w8], s2[1][w8+8]));
    float mx = fmaxf(fmaxf(fmaxf(mA[0],mA[1]), fmaxf(mA[2],mA[3])),
                     fmaxf(fmaxf(mA[4],mA[5]), fmaxf(mA[6],mA[7])));
    mx = fmaxf(mx, __shfl_xor(mx, 32, 64));

    // defer-max: only rescale when max grew by > 8 (log2 domain, P <= 256)
    if(__any(mx > m + 8.0f)){
      float mn = fmaxf(m, mx);
      float fac = exp2f(m - mn);
      m = mn;
      lsum *= fac;
      #pragma unroll
      for(int mt=0; mt<2; ++mt)
        #pragma unroll
        for(int rg=0; rg<16; ++rg) oT[mt][rg] *= fac;
    }

    // exp + row-sum (tree + 1 shuffle)
    #pragma unroll
    for(int kt=0; kt<2; ++kt)
      #pragma unroll
      for(int rg=0; rg<16; ++rg) s2[kt][rg] = exp2f(s2[kt][rg] - m);
    float sA[8];
    #pragma unroll
    for(int w8=0; w8<8; ++w8)
      sA[w8] = (s2[0][w8] + s2[0][w8+8]) + (s2[1][w8] + s2[1][w8+8]);
    float rs = ((sA[0]+sA[1]) + (sA[2]+sA[3])) + ((sA[4]+sA[5]) + (sA[6]+sA[7]));
    rs += __shfl_xor(rs, 32, 64);
    lsum += rs;

    // pack P to bf16 pairs: pd[kt][w] = {p[2w] lo, p[2w+1] hi}
    int pd[2][8];
    #pragma unroll
    for(int kt=0; kt<2; ++kt)
      #pragma unroll
      for(int w8=0; w8<8; ++w8)
        asm("v_cvt_pk_bf16_f32 %0, %1, %2"
            : "=v"(pd[kt][w8]) : "v"(s2[kt][2*w8]), "v"(s2[kt][2*w8+1]));

    // PV: O^T += V^T * P^T ; B-frag for step ss = pd[ss>>1][4*(ss&1) .. +3]
    #pragma unroll
    for(int ss=0; ss<4; ++ss){
      union { int i4[4]; s16x8 v8; } pf;
      #pragma unroll
      for(int e=0; e<4; ++e) pf.i4[e] = pd[ss>>1][4*(ss&1) + e];
      #pragma unroll
      for(int mt=0; mt<2; ++mt)
        oT[mt] = __builtin_amdgcn_mfma_f32_32x32x16_bf16(vf[mt][ss].v8, pf.v8, oT[mt], 0,0,0);
    }

    // roll K prefetch
    #pragma unroll
    for(int kt=0; kt<2; ++kt)
      #pragma unroll
      for(int ks=0; ks<4; ++ks) kf[kt][ks] = kn[kt][ks];
  }

  if(nc == 1){
    float inv = 1.0f/lsum;
    long obase = ((long)(b*NSEQ + t*32 + q5))*NHID + hq*HD;
    #pragma unroll
    for(int mt=0; mt<2; ++mt)
      #pragma unroll
      for(int rq=0; rq<4; ++rq){
        int d0 = mt*32 + 8*rq + 4*h;
        s16x4 g4 = *(const s16x4*)(gateb + obase + d0);
        s16x4 o4;
        #pragma unroll
        for(int e=0; e<4; ++e)
          o4[e] = f2bf(oT[mt][4*rq + e]*inv*bf2f((unsigned short)g4[e]));
        *(s16x4*)(Og + obase + d0) = o4;
      }
  } else {
    int g = t >> 4;
    int poff = (g==1) ? (t-16)*2 : (g==2) ? 32 + (t-32)*3 : 80 + (t-48)*4;
    float* pb = Pbuf + ((long)head*144 + poff + ci)*2112;
    #pragma unroll
    for(int mt=0; mt<2; ++mt)
      #pragma unroll
      for(int rg=0; rg<16; ++rg){
        int d = mt*32 + (rg&3) + 8*(rg>>2) + 4*h;
        pb[q5*64 + d] = oT[mt][rg];
      }
    if(h == 0 && ((tid >> 5) & 1) == 0){
      pb[2048 + q5] = m;
      pb[2080 + q5] = lsum;
    }
  }
}

// ---------------- split-K combine (t >= 16 tiles) ----------------

__global__ __launch_bounds__(64)
void attn_combine_kernel(const float* __restrict__ Pbuf, const short* __restrict__ gateb,
                         short* __restrict__ Og)
{
  int t = 16 + blockIdx.x;        // 16..63
  int head = blockIdx.y;          // 0..27
  int hg = head % 7; int kvb = head / 7; int b = kvb >> 1; int kv = kvb & 1;
  int hq = kv*7 + hg;
  int nc = (t >> 4) + 1;          // 2..4
  int g = t >> 4;
  int poff = (g==1) ? (t-16)*2 : (g==2) ? 32 + (t-32)*3 : 80 + (t-48)*4;
  const float* pb0 = Pbuf + ((long)head*144 + poff)*2112;

  int l = threadIdx.x;
  int q5 = l & 31;
  int d0 = (l >> 5)*32;

  float ms[4];
  float M = -__builtin_inff();
  #pragma unroll
  for(int i=0;i<4;i++){
    ms[i] = (i < nc) ? pb0[i*2112 + 2048 + q5] : -__builtin_inff();
    M = fmaxf(M, ms[i]);
  }
  float L = 0.f;
  f32x4 Oa[8];
  #pragma unroll
  for(int c=0;c<8;c++) Oa[c] = (f32x4){0.f,0.f,0.f,0.f};
  #pragma unroll
  for(int i=0;i<4;i++){
    if(i < nc){
      float fac = exp2f(ms[i] - M);
      L += pb0[i*2112 + 2080 + q5] * fac;
      const float* po = pb0 + i*2112 + q5*64 + d0;
      #pragma unroll
      for(int c=0;c<8;c++){
        f32x4 v = *(const f32x4*)(po + 4*c);
        #pragma unroll
        for(int e=0;e<4;e++) Oa[c][e] += v[e]*fac;
      }
    }
  }
  float inv = 1.0f/L;
  long obase = ((long)(b*NSEQ + t*32 + q5))*NHID + hq*HD + d0;
  #pragma unroll
  for(int c=0;c<8;c++){
    s16x4 g4 = *(const s16x4*)(gateb + obase + 4*c);
    s16x4 o4;
    #pragma unroll
    for(int e=0;e<4;e++)
      o4[e] = f2bf(Oa[c][e]*inv*bf2f((unsigned short)g4[e]));
    *(s16x4*)(Og + obase + 4*c) = o4;
  }
}

// ---------------- launch ----------------

extern "C" void kernel_launch(void* const* d_in, const int* in_sizes, int n_in,
                              void* d_out, int out_size, void* d_ws, size_t ws_size,
                              hipStream_t stream)
{
  const float* hs  = (const float*)d_in[0];
  const int*   pos = (const int*)d_in[1];
  const float* Wq  = (const float*)d_in[2];
  const float* bq  = (const float*)d_in[3];
  const float* Wk  = (const float*)d_in[4];
  const float* bk  = (const float*)d_in[5];
  const float* Wv  = (const float*)d_in[6];
  const float* bv  = (const float*)d_in[7];
  const float* Wg  = (const float*)d_in[8];
  const float* Wo  = (const float*)d_in[9];
  float* out = (float*)d_out;

  char* p = (char*)d_ws;
  short* Xb    = (short*)p; p += (size_t)NROW*NHID*2;
  short* WcatT = (short*)p; p += (size_t)NCAT*NHID*2;
  short* WoT   = (short*)p; p += (size_t)NHID*NHID*2;
  float* ct    = (float*)p; p += (size_t)NROW*32*4;
  float* st    = (float*)p; p += (size_t)NROW*32*4;
  short* Qb    = (short*)p; p += (size_t)NB*NHQ*NSEQ*HD*2;
  short* Kb    = (short*)p; p += (size_t)NB*NHKV*NSEQ*HD*2;
  short* Vb    = (short*)p; p += (size_t)NB*NHKV*NSEQ*HD*2;
  short* VbT   = (short*)p; p += (size_t)NB*NHKV*NSEQ*HD*2;
  short* gateb = (short*)p; p += (size_t)NROW*NHID*2;
  short* Og    = (short*)p; p += (size_t)NROW*NHID*2;
  float* Pbuf  = (float*)p; p += (size_t)28*144*2112*4;   // 34 MB split-K partials

  pack_x_kernel<<<(NROW*NHID+255)/256, 256, 0, stream>>>(hs, Xb, NROW*NHID);
  pack_wcat_kernel<<<(NCAT*NHID+255)/256, 256, 0, stream>>>(Wq, Wk, Wv, Wg, WcatT);
  pack_wo_kernel<<<(NHID*NHID+255)/256, 256, 0, stream>>>(Wo, WoT);
  rope_table_kernel<<<(NROW*32+255)/256, 256, 0, stream>>>(pos, ct, st);

  gemm_kernel<0><<<dim3(NCAT/128, NROW/128), 256, 0, stream>>>(
      Xb, WcatT, NCAT, NHID, bq, bk, bv, ct, st, Qb, Kb, Vb, gateb, nullptr);

  transpose_v_kernel<<<dim3(NSEQ/64, NB*NHKV), 256, 0, stream>>>(Vb, VbT);

  attn3_kernel<<<dim3(160, 4), 448, 0, stream>>>(Qb, Kb, VbT, gateb, Og, Pbuf);
  attn_combine_kernel<<<dim3(48, 28), 64, 0, stream>>>(Pbuf, gateb, Og);

  gemm_kernel<1><<<dim3(NHID/128, NROW/128), 256, 0, stream>>>(
      Og, WoT, NHID, NHID, nullptr, nullptr, nullptr, nullptr, nullptr,
      nullptr, nullptr, nullptr, nullptr, out);
}

// Round 9
// 145.501 us; speedup vs baseline: 1.5112x; 1.5112x over previous
//
#include <hip/hip_runtime.h>
#include <hip/hip_bf16.h>

typedef short s16x4 __attribute__((ext_vector_type(4)));
typedef short s16x8 __attribute__((ext_vector_type(8)));
typedef float f32x4 __attribute__((ext_vector_type(4)));
typedef float f32x16 __attribute__((ext_vector_type(16)));

#define NB 2
#define NSEQ 2048
#define NHID 896
#define NHQ 14
#define NHKV 2
#define HD 64
#define NROW (NB*NSEQ)     // 4096
#define NCAT 2048          // 896 Q | 128 K | 128 V | 896 gate
#define PS 40              // padded LDS row stride in shorts (80B, 16B-aligned)
#define QSC 0.18033688011112042f   // (1/8) * log2(e), folded into Q at projection

__device__ __forceinline__ float bf2f(unsigned short s){
  union { float f; unsigned u; } v; v.u = ((unsigned)s) << 16; return v.f;
}
__device__ __forceinline__ short f2bf(float f){
  union { float f; unsigned u; } v; v.f = f;
  unsigned u = v.u + 0x7fffu + ((v.u >> 16) & 1u);
  return (short)(u >> 16);
}

// ---------------- packing kernels ----------------

__global__ void pack_x_kernel(const float* __restrict__ x, short* __restrict__ xb, int n){
  int i = blockIdx.x*256 + threadIdx.x;
  if(i < n) xb[i] = f2bf(x[i]);
}

__global__ void pack_wcat_kernel(const float* __restrict__ Wq, const float* __restrict__ Wk,
                                 const float* __restrict__ Wv, const float* __restrict__ Wg,
                                 short* __restrict__ WcatT){
  int t = blockIdx.x*256 + threadIdx.x;
  if(t >= NCAT*NHID) return;
  int k = t % NHID, c = t / NHID;
  float v;
  if(c < 896)       v = Wq[k*896 + c];
  else if(c < 1024) v = Wk[k*128 + (c-896)];
  else if(c < 1152) v = Wv[k*128 + (c-1024)];
  else              v = Wg[k*896 + (c-1152)];
  WcatT[t] = f2bf(v);
}

__global__ void pack_wo_kernel(const float* __restrict__ Wo, short* __restrict__ WoT){
  int t = blockIdx.x*256 + threadIdx.x;
  if(t >= NHID*NHID) return;
  int k = t % NHID, c = t / NHID;
  WoT[t] = f2bf(Wo[k*896 + c]);
}

__global__ void rope_table_kernel(const int* __restrict__ pos, float* __restrict__ ct,
                                  float* __restrict__ st){
  int t = blockIdx.x*256 + threadIdx.x;
  if(t >= NROW*32) return;
  int i = t & 31, rn = t >> 5;
  float p = (float)pos[rn];
  float inv = powf(1.0e6f, -(float)i * (1.0f/32.0f));
  float a = p * inv;
  ct[t] = cosf(a);
  st[t] = sinf(a);
}

// ---------------- K/V fragment packing ----------------
// Emits Kp/Vp in per-lane fragment order so every in-loop attention load is
// 64 lanes x 16B contiguous (kills the 32-line-per-instruction gathers).
// Kp[bh][j][f=kt*4+ks][l] = K[bh][j*64+kt*32+(l&31)][16ks+8*(l>>5) .. +8)
// Vp[bh][j][f=mt*4+ss][l] : shorts[e]  = V[bh][j*64+16ss+4*(l>>5)+e  ][mt*32+(l&31)]
//                           shorts[4+e]= V[bh][j*64+16ss+4*(l>>5)+8+e][mt*32+(l&31)]
// (V-transpose folded in; replaces the old transpose_v/VbT path.)

__global__ __launch_bounds__(256)
void pack_kv_kernel(const short* __restrict__ Kb, const short* __restrict__ Vb,
                    short* __restrict__ Kp, short* __restrict__ Vp){
  __shared__ short Kl[64][72];
  __shared__ short Vl[64][72];   // Vl[n][d]
  int j  = blockIdx.x;      // 0..31
  int bh = blockIdx.y;      // 0..3
  int tid = threadIdx.x;
  #pragma unroll
  for(int it=0; it<2; ++it){
    int idx = it*256 + tid;       // 0..511
    int r = idx >> 3, c0 = (idx & 7)*8;
    *(s16x8*)&Kl[r][c0] = *(const s16x8*)(Kb + ((long)bh*NSEQ + j*64 + r)*HD + c0);
    *(s16x8*)&Vl[r][c0] = *(const s16x8*)(Vb + ((long)bh*NSEQ + j*64 + r)*HD + c0);
  }
  __syncthreads();
  long base = ((long)bh*32 + j)*4096;
  #pragma unroll
  for(int it=0; it<2; ++it){
    int c = it*256 + tid;         // fragment-chunk 0..511
    int f = c >> 6, l = c & 63;
    int kt = f >> 2, ks = f & 3, h = l >> 5, r5 = l & 31;
    *(s16x8*)(Kp + base + f*512 + l*8) = *(const s16x8*)&Kl[kt*32 + r5][16*ks + 8*h];
    s16x8 o;
    #pragma unroll
    for(int e=0;e<4;e++){
      o[e]   = Vl[16*ks + 4*h + e    ][kt*32 + r5];
      o[4+e] = Vl[16*ks + 4*h + 8 + e][kt*32 + r5];
    }
    *(s16x8*)(Vp + base + f*512 + l*8) = o;
  }
}

// ---------------- GEMM (bf16 MFMA, reg-staged LDS double-buffer) ----------------
// EPI=0: QKVG epilogue (Q pre-scaled by QSC), EPI=1: plain f32 out
// NOTE: every loop touching acc[][] MUST be #pragma unroll'd (rule #20).

template<int EPI>
__global__ __launch_bounds__(256)
void gemm_kernel(const short* __restrict__ A, const short* __restrict__ Bt,
                 int Ncols, int K,
                 const float* __restrict__ bq, const float* __restrict__ bk,
                 const float* __restrict__ bv,
                 const float* __restrict__ ct, const float* __restrict__ st,
                 short* __restrict__ Qb, short* __restrict__ Kb, short* __restrict__ Vb,
                 short* __restrict__ gateb, float* __restrict__ outp)
{
  __shared__ short As[2][128*PS];
  __shared__ short Bs[2][128*PS];

  int tid = threadIdx.x;
  int w = tid >> 6, l = tid & 63;
  int wm = w >> 1, wn = w & 1;
  int row0 = blockIdx.y*128;
  int col0 = blockIdx.x*128;
  int lo = l & 15, hi = l >> 4;

  const short* A0 = A  + (long)row0*K;
  const short* B0 = Bt + (long)col0*K;

  f32x4 acc[4][4];
  #pragma unroll
  for(int mi=0;mi<4;mi++)
    #pragma unroll
    for(int ni=0;ni<4;ni++) acc[mi][ni] = (f32x4){0.f,0.f,0.f,0.f};

  int srow = tid >> 2;
  int scol = (tid & 3)*8;

  s16x8 ra[2], rb[2];
  auto gload = [&](int k0){
    #pragma unroll
    for(int i=0;i<2;i++){
      int row = i*64 + srow;
      ra[i] = *(const s16x8*)(A0 + (long)row*K + k0 + scol);
      rb[i] = *(const s16x8*)(B0 + (long)row*K + k0 + scol);
    }
  };
  auto swrite = [&](int buf){
    #pragma unroll
    for(int i=0;i<2;i++){
      int row = i*64 + srow;
      *(s16x8*)&As[buf][row*PS + scol] = ra[i];
      *(s16x8*)&Bs[buf][row*PS + scol] = rb[i];
    }
  };

  gload(0);
  swrite(0);

  int NIT = K >> 5;
  int cur = 0;
  for(int it=0; it<NIT; ++it){
    __syncthreads();
    if(it+1 < NIT) gload((it+1)*32);

    s16x8 af[4], bf[4];
    #pragma unroll
    for(int mi=0;mi<4;mi++) af[mi] = *(const s16x8*)&As[cur][(wm*64 + 16*mi + lo)*PS + 8*hi];
    #pragma unroll
    for(int ni=0;ni<4;ni++) bf[ni] = *(const s16x8*)&Bs[cur][(wn*64 + 16*ni + lo)*PS + 8*hi];
    #pragma unroll
    for(int mi=0;mi<4;mi++)
      #pragma unroll
      for(int ni=0;ni<4;ni++)
        acc[mi][ni] = __builtin_amdgcn_mfma_f32_16x16x32_bf16(af[mi], bf[ni], acc[mi][ni], 0,0,0);

    if(it+1 < NIT) swrite(cur^1);
    cur ^= 1;
  }

  if(EPI == 1){
    #pragma unroll
    for(int mi=0;mi<4;mi++)
      #pragma unroll
      for(int ni=0;ni<4;ni++)
        #pragma unroll
        for(int rg=0;rg<4;rg++){
          int r = row0 + wm*64 + 16*mi + 4*hi + rg;
          int c = col0 + wn*64 + lo + 16*ni;
          outp[(long)r*Ncols + c] = acc[mi][ni][rg];
        }
  } else {
    int wcol0 = col0 + wn*64;
    int region = (wcol0 < 896) ? 0 : (wcol0 < 1024) ? 1 : (wcol0 < 1152) ? 2 : 3;
    #pragma unroll
    for(int mi=0;mi<4;mi++){
      #pragma unroll
      for(int rg=0;rg<4;rg++){
        int r = row0 + wm*64 + 16*mi + 4*hi + rg;
        int b = r >> 11, n = r & 2047;
        if(region <= 1){
          #pragma unroll
          for(int ni=0;ni<2;ni++){
            int c  = wcol0 + lo + 16*ni;
            int cb = (region==0) ? c : (c-896);
            int hh = cb >> 6, dlo = cb & 63;
            float bl = (region==0) ? bq[c]    : bk[cb];
            float bh = (region==0) ? bq[c+32] : bk[cb+32];
            float ylo = acc[mi][ni  ][rg] + bl;
            float yhi = acc[mi][ni+2][rg] + bh;
            float cs = ct[r*32 + dlo];
            float sn = st[r*32 + dlo];
            float olo = ylo*cs - yhi*sn;
            float ohi = yhi*cs + ylo*sn;
            if(region==0){
              long base = ((long)(b*NHQ + hh)*NSEQ + n)*HD;
              Qb[base + dlo]      = f2bf(olo*QSC);
              Qb[base + dlo + 32] = f2bf(ohi*QSC);
            } else {
              long base = ((long)(b*NHKV + hh)*NSEQ + n)*HD;
              Kb[base + dlo]      = f2bf(olo);
              Kb[base + dlo + 32] = f2bf(ohi);
            }
          }
        } else if(region == 2){
          #pragma unroll
          for(int ni=0;ni<4;ni++){
            int c = wcol0 + lo + 16*ni;
            int cv = c - 1024;
            int hh = cv >> 6, d = cv & 63;
            float y = acc[mi][ni][rg] + bv[cv];
            Vb[((long)(b*NHKV + hh)*NSEQ + n)*HD + d] = f2bf(y);
          }
        } else {
          #pragma unroll
          for(int ni=0;ni<4;ni++){
            int c = wcol0 + lo + 16*ni;
            int cg = c - 1152;
            float y = acc[mi][ni][rg];
            gateb[(long)r*NHID + cg] = f2bf(1.0f/(1.0f + __expf(-y)));
          }
        }
      }
    }
  }
}

// ---------------- split-K flash attention, 7 GQA heads per block ----------------
// All in-loop K/V loads are coalesced reads of the packed fragment buffers.
// Per-wave math identical to the verified R7/R8 stream. Chunk map & combine
// unchanged.

__global__ __launch_bounds__(448)
void attn3_kernel(const short* __restrict__ Qb, const short* __restrict__ Kp,
                  const short* __restrict__ Vp, const short* __restrict__ gateb,
                  short* __restrict__ Og, float* __restrict__ Pbuf)
{
  int tid = threadIdx.x;
  int l = tid & 63;
  int q5 = l & 31, h = l >> 5;
  int hg = tid >> 6;              // wave id = head-in-group 0..6

  int s = blockIdx.x;             // 0..159 chunk slot
  int kvb = blockIdx.y;           // 0..3 = (b,kv)
  int b = kvb >> 1, kv = kvb & 1;
  int hq = kv*7 + hg;
  int head = kvb*7 + hg;          // Pbuf head index (matches combine decode)

  int t, ci, nc;
  if(s < 16){ t = s; ci = 0; nc = 1; }
  else if(s < 48){ int r = s-16; t = 16 + (r>>1); ci = r & 1; nc = 2; }
  else if(s < 96){ int r = s-48; t = 32 + r/3; ci = r - (r/3)*3; nc = 3; }
  else { int r = s-96; t = 48 + (r>>2); ci = r & 3; nc = 4; }

  int qg = t*32 + q5;
  int jcausal = (t*32 + 31) >> 6;           // diagonal 64-key group; in last chunk
  int j0 = ci*8;
  int j1 = (ci == nc-1) ? jcausal : (j0 + 7);

  const short* qrow = Qb + ((long)(b*NHQ + hq)*NSEQ + t*32 + q5)*HD;
  s16x8 qf[4];
  #pragma unroll
  for(int ks=0; ks<4; ++ks) qf[ks] = *(const s16x8*)(qrow + 16*ks + 8*h);

  const short* kpb = Kp + (long)kvb*32*4096 + l*8;
  const short* vpb = Vp + (long)kvb*32*4096 + l*8;

  f32x16 oT[2];
  #pragma unroll
  for(int mt=0; mt<2; ++mt)
    #pragma unroll
    for(int rg=0; rg<16; ++rg) oT[mt][rg] = 0.f;
  float m = -__builtin_inff(), lsum = 0.f;

  // preload K group j0 (coalesced fragment reads)
  s16x8 kf[2][4];
  #pragma unroll
  for(int kt=0; kt<2; ++kt)
    #pragma unroll
    for(int ks=0; ks<4; ++ks)
      kf[kt][ks] = *(const s16x8*)(kpb + (long)j0*4096 + (kt*4+ks)*512);

  for(int j=j0; j<=j1; ++j){
    // V fragments (coalesced)
    s16x8 vf[2][4];
    #pragma unroll
    for(int mt=0; mt<2; ++mt)
      #pragma unroll
      for(int ss=0; ss<4; ++ss)
        vf[mt][ss] = *(const s16x8*)(vpb + (long)j*4096 + (mt*4+ss)*512);

    // S^T = K * Q^T (softmax scale pre-folded into Q, log2 domain)
    f32x16 s2[2];
    #pragma unroll
    for(int kt=0; kt<2; ++kt)
      #pragma unroll
      for(int rg=0; rg<16; ++rg) s2[kt][rg] = 0.f;
    #pragma unroll
    for(int kt=0; kt<2; ++kt)
      #pragma unroll
      for(int ks=0; ks<4; ++ks)
        s2[kt] = __builtin_amdgcn_mfma_f32_32x32x16_bf16(kf[kt][ks], qf[ks], s2[kt], 0,0,0);

    // prefetch next K group while softmax+PV run
    int jn = (j < j1) ? j+1 : j;
    s16x8 kn[2][4];
    #pragma unroll
    for(int kt=0; kt<2; ++kt)
      #pragma unroll
      for(int ks=0; ks<4; ++ks)
        kn[kt][ks] = *(const s16x8*)(kpb + (long)jn*4096 + (kt*4+ks)*512);

    // causal mask (diagonal group only). key row = (rg&3)+8*(rg>>2)+4h
    if(j == jcausal){
      #pragma unroll
      for(int kt=0; kt<2; ++kt)
        #pragma unroll
        for(int rg=0; rg<16; ++rg){
          int kl = j*64 + kt*32 + (rg&3) + 8*(rg>>2) + 4*h;
          if(kl > qg) s2[kt][rg] = -__builtin_inff();
        }
    }

    // row-max: in-lane tree + 1 shuffle across h
    float mA[8];
    #pragma unroll
    for(int w8=0; w8<8; ++w8)
      mA[w8] = fmaxf(fmaxf(s2[0][w8], s2[0][w8+8]), fmaxf(s2[1][w8], s2[1][w8+8]));
    float mx = fmaxf(fmaxf(fmaxf(mA[0],mA[1]), fmaxf(mA[2],mA[3])),
                     fmaxf(fmaxf(mA[4],mA[5]), fmaxf(mA[6],mA[7])));
    mx = fmaxf(mx, __shfl_xor(mx, 32, 64));

    // defer-max: only rescale when max grew by > 8 (log2 domain, P <= 256)
    if(__any(mx > m + 8.0f)){
      float mn = fmaxf(m, mx);
      float fac = exp2f(m - mn);
      m = mn;
      lsum *= fac;
      #pragma unroll
      for(int mt=0; mt<2; ++mt)
        #pragma unroll
        for(int rg=0; rg<16; ++rg) oT[mt][rg] *= fac;
    }

    // exp + row-sum (tree + 1 shuffle)
    #pragma unroll
    for(int kt=0; kt<2; ++kt)
      #pragma unroll
      for(int rg=0; rg<16; ++rg) s2[kt][rg] = exp2f(s2[kt][rg] - m);
    float sA[8];
    #pragma unroll
    for(int w8=0; w8<8; ++w8)
      sA[w8] = (s2[0][w8] + s2[0][w8+8]) + (s2[1][w8] + s2[1][w8+8]);
    float rs = ((sA[0]+sA[1]) + (sA[2]+sA[3])) + ((sA[4]+sA[5]) + (sA[6]+sA[7]));
    rs += __shfl_xor(rs, 32, 64);
    lsum += rs;

    // pack P to bf16 pairs: pd[kt][w] = {p[2w] lo, p[2w+1] hi}
    int pd[2][8];
    #pragma unroll
    for(int kt=0; kt<2; ++kt)
      #pragma unroll
      for(int w8=0; w8<8; ++w8)
        asm("v_cvt_pk_bf16_f32 %0, %1, %2"
            : "=v"(pd[kt][w8]) : "v"(s2[kt][2*w8]), "v"(s2[kt][2*w8+1]));

    // PV: O^T += V^T * P^T ; B-frag for step ss = pd[ss>>1][4*(ss&1) .. +3]
    #pragma unroll
    for(int ss=0; ss<4; ++ss){
      union { int i4[4]; s16x8 v8; } pf;
      #pragma unroll
      for(int e=0; e<4; ++e) pf.i4[e] = pd[ss>>1][4*(ss&1) + e];
      #pragma unroll
      for(int mt=0; mt<2; ++mt)
        oT[mt] = __builtin_amdgcn_mfma_f32_32x32x16_bf16(vf[mt][ss], pf.v8, oT[mt], 0,0,0);
    }

    // roll K prefetch
    #pragma unroll
    for(int kt=0; kt<2; ++kt)
      #pragma unroll
      for(int ks=0; ks<4; ++ks) kf[kt][ks] = kn[kt][ks];
  }

  if(nc == 1){
    float inv = 1.0f/lsum;
    long obase = ((long)(b*NSEQ + t*32 + q5))*NHID + hq*HD;
    #pragma unroll
    for(int mt=0; mt<2; ++mt)
      #pragma unroll
      for(int rq=0; rq<4; ++rq){
        int d0 = mt*32 + 8*rq + 4*h;
        s16x4 g4 = *(const s16x4*)(gateb + obase + d0);
        s16x4 o4;
        #pragma unroll
        for(int e=0; e<4; ++e)
          o4[e] = f2bf(oT[mt][4*rq + e]*inv*bf2f((unsigned short)g4[e]));
        *(s16x4*)(Og + obase + d0) = o4;
      }
  } else {
    int g = t >> 4;
    int poff = (g==1) ? (t-16)*2 : (g==2) ? 32 + (t-32)*3 : 80 + (t-48)*4;
    float* pb = Pbuf + ((long)head*144 + poff + ci)*2112;
    #pragma unroll
    for(int mt=0; mt<2; ++mt)
      #pragma unroll
      for(int rg=0; rg<16; ++rg){
        int d = mt*32 + (rg&3) + 8*(rg>>2) + 4*h;
        pb[q5*64 + d] = oT[mt][rg];
      }
    if(h == 0){
      pb[2048 + q5] = m;
      pb[2080 + q5] = lsum;
    }
  }
}

// ---------------- split-K combine (t >= 16 tiles) ----------------

__global__ __launch_bounds__(64)
void attn_combine_kernel(const float* __restrict__ Pbuf, const short* __restrict__ gateb,
                         short* __restrict__ Og)
{
  int t = 16 + blockIdx.x;        // 16..63
  int head = blockIdx.y;          // 0..27
  int hg = head % 7; int kvb = head / 7; int b = kvb >> 1; int kv = kvb & 1;
  int hq = kv*7 + hg;
  int nc = (t >> 4) + 1;          // 2..4
  int g = t >> 4;
  int poff = (g==1) ? (t-16)*2 : (g==2) ? 32 + (t-32)*3 : 80 + (t-48)*4;
  const float* pb0 = Pbuf + ((long)head*144 + poff)*2112;

  int l = threadIdx.x;
  int q5 = l & 31;
  int d0 = (l >> 5)*32;

  float ms[4];
  float M = -__builtin_inff();
  #pragma unroll
  for(int i=0;i<4;i++){
    ms[i] = (i < nc) ? pb0[i*2112 + 2048 + q5] : -__builtin_inff();
    M = fmaxf(M, ms[i]);
  }
  float L = 0.f;
  f32x4 Oa[8];
  #pragma unroll
  for(int c=0;c<8;c++) Oa[c] = (f32x4){0.f,0.f,0.f,0.f};
  #pragma unroll
  for(int i=0;i<4;i++){
    if(i < nc){
      float fac = exp2f(ms[i] - M);
      L += pb0[i*2112 + 2080 + q5] * fac;
      const float* po = pb0 + i*2112 + q5*64 + d0;
      #pragma unroll
      for(int c=0;c<8;c++){
        f32x4 v = *(const f32x4*)(po + 4*c);
        #pragma unroll
        for(int e=0;e<4;e++) Oa[c][e] += v[e]*fac;
      }
    }
  }
  float inv = 1.0f/L;
  long obase = ((long)(b*NSEQ + t*32 + q5))*NHID + hq*HD + d0;
  #pragma unroll
  for(int c=0;c<8;c++){
    s16x4 g4 = *(const s16x4*)(gateb + obase + 4*c);
    s16x4 o4;
    #pragma unroll
    for(int e=0;e<4;e++)
      o4[e] = f2bf(Oa[c][e]*inv*bf2f((unsigned short)g4[e]));
    *(s16x4*)(Og + obase + 4*c) = o4;
  }
}

// ---------------- launch ----------------

extern "C" void kernel_launch(void* const* d_in, const int* in_sizes, int n_in,
                              void* d_out, int out_size, void* d_ws, size_t ws_size,
                              hipStream_t stream)
{
  const float* hs  = (const float*)d_in[0];
  const int*   pos = (const int*)d_in[1];
  const float* Wq  = (const float*)d_in[2];
  const float* bq  = (const float*)d_in[3];
  const float* Wk  = (const float*)d_in[4];
  const float* bk  = (const float*)d_in[5];
  const float* Wv  = (const float*)d_in[6];
  const float* bv  = (const float*)d_in[7];
  const float* Wg  = (const float*)d_in[8];
  const float* Wo  = (const float*)d_in[9];
  float* out = (float*)d_out;

  char* p = (char*)d_ws;
  short* Xb    = (short*)p; p += (size_t)NROW*NHID*2;
  short* WcatT = (short*)p; p += (size_t)NCAT*NHID*2;
  short* WoT   = (short*)p; p += (size_t)NHID*NHID*2;
  float* ct    = (float*)p; p += (size_t)NROW*32*4;
  float* st    = (float*)p; p += (size_t)NROW*32*4;
  short* Qb    = (short*)p; p += (size_t)NB*NHQ*NSEQ*HD*2;
  short* Kb    = (short*)p; p += (size_t)NB*NHKV*NSEQ*HD*2;
  short* Vb    = (short*)p; p += (size_t)NB*NHKV*NSEQ*HD*2;
  short* Kp    = (short*)p; p += (size_t)4*32*4096*2;     // packed K fragments (1 MB)
  short* Vp    = (short*)p; p += (size_t)4*32*4096*2;     // packed V fragments (1 MB)
  short* gateb = (short*)p; p += (size_t)NROW*NHID*2;
  short* Og    = (short*)p; p += (size_t)NROW*NHID*2;
  float* Pbuf  = (float*)p; p += (size_t)28*144*2112*4;   // 34 MB split-K partials

  pack_x_kernel<<<(NROW*NHID+255)/256, 256, 0, stream>>>(hs, Xb, NROW*NHID);
  pack_wcat_kernel<<<(NCAT*NHID+255)/256, 256, 0, stream>>>(Wq, Wk, Wv, Wg, WcatT);
  pack_wo_kernel<<<(NHID*NHID+255)/256, 256, 0, stream>>>(Wo, WoT);
  rope_table_kernel<<<(NROW*32+255)/256, 256, 0, stream>>>(pos, ct, st);

  gemm_kernel<0><<<dim3(NCAT/128, NROW/128), 256, 0, stream>>>(
      Xb, WcatT, NCAT, NHID, bq, bk, bv, ct, st, Qb, Kb, Vb, gateb, nullptr);

  pack_kv_kernel<<<dim3(32, 4), 256, 0, stream>>>(Kb, Vb, Kp, Vp);

  attn3_kernel<<<dim3(160, 4), 448, 0, stream>>>(Qb, Kp, Vp, gateb, Og, Pbuf);
  attn_combine_kernel<<<dim3(48, 28), 64, 0, stream>>>(Pbuf, gateb, Og);

  gemm_kernel<1><<<dim3(NHID/128, NROW/128), 256, 0, stream>>>(
      Og, WoT, NHID, NHID, nullptr, nullptr, nullptr, nullptr, nullptr,
      nullptr, nullptr, nullptr, nullptr, out);
}

// Round 11
// 134.992 us; speedup vs baseline: 1.6289x; 1.0779x over previous
//
#include <hip/hip_runtime.h>
#include <hip/hip_bf16.h>

typedef short s16x4 __attribute__((ext_vector_type(4)));
typedef short s16x8 __attribute__((ext_vector_type(8)));
typedef float f32x4 __attribute__((ext_vector_type(4)));
typedef float f32x16 __attribute__((ext_vector_type(16)));

#define NB 2
#define NSEQ 2048
#define NHID 896
#define NHQ 14
#define NHKV 2
#define HD 64
#define NROW (NB*NSEQ)     // 4096
#define NCAT 2048          // 896 Q | 128 K | 128 V | 896 gate
#define PS 40              // padded LDS row stride in shorts (80B, 16B-aligned)
#define QSC 0.18033688011112042f   // (1/8) * log2(e), folded into Q at projection

__device__ __forceinline__ float bf2f(unsigned short s){
  union { float f; unsigned u; } v; v.u = ((unsigned)s) << 16; return v.f;
}
__device__ __forceinline__ short f2bf(float f){
  union { float f; unsigned u; } v; v.f = f;
  unsigned u = v.u + 0x7fffu + ((v.u >> 16) & 1u);
  return (short)(u >> 16);
}

// ---------------- packing kernels ----------------

__global__ void pack_x_kernel(const float* __restrict__ x, short* __restrict__ xb, int n){
  int i = blockIdx.x*256 + threadIdx.x;
  if(i < n) xb[i] = f2bf(x[i]);
}

// LDS-tiled transpose pack: WcatT[c][k] = W_region(k, c), coalesced both sides.
// (The old per-element version was a stride-3.6KB gather: 1 line per lane.)
__global__ __launch_bounds__(256)
void pack_wcat_t_kernel(const float* __restrict__ Wq, const float* __restrict__ Wk,
                        const float* __restrict__ Wv, const float* __restrict__ Wg,
                        short* __restrict__ WcatT){
  __shared__ short T[64][73];
  int c0 = blockIdx.x*64, k0 = blockIdx.y*64;
  const float* src; int width, cb;
  if(c0 < 896){ src = Wq; width = 896; cb = c0; }
  else if(c0 < 1024){ src = Wk; width = 128; cb = c0-896; }
  else if(c0 < 1152){ src = Wv; width = 128; cb = c0-1024; }
  else { src = Wg; width = 896; cb = c0-1152; }
  int tid = threadIdx.x;
  #pragma unroll
  for(int it=0; it<4; ++it){
    int idx = it*256 + tid;           // 0..1023
    int r = idx >> 4, q = idx & 15;   // r = k-local, q = float4 chunk of c
    f32x4 v = *(const f32x4*)(src + (long)(k0+r)*width + cb + q*4);
    #pragma unroll
    for(int e=0;e<4;e++) T[r][q*4+e] = f2bf(v[e]);
  }
  __syncthreads();
  #pragma unroll
  for(int it=0; it<2; ++it){
    int idx = it*256 + tid;           // 0..511
    int c = idx >> 3, ch = idx & 7;
    s16x8 o;
    #pragma unroll
    for(int e=0;e<8;e++) o[e] = T[ch*8+e][c];
    *(s16x8*)(WcatT + (long)(c0+c)*NHID + k0 + ch*8) = o;
  }
}

__global__ __launch_bounds__(256)
void pack_wo_t_kernel(const float* __restrict__ Wo, short* __restrict__ WoT){
  __shared__ short T[64][73];
  int c0 = blockIdx.x*64, k0 = blockIdx.y*64;
  int tid = threadIdx.x;
  #pragma unroll
  for(int it=0; it<4; ++it){
    int idx = it*256 + tid;
    int r = idx >> 4, q = idx & 15;
    f32x4 v = *(const f32x4*)(Wo + (long)(k0+r)*896 + c0 + q*4);
    #pragma unroll
    for(int e=0;e<4;e++) T[r][q*4+e] = f2bf(v[e]);
  }
  __syncthreads();
  #pragma unroll
  for(int it=0; it<2; ++it){
    int idx = it*256 + tid;
    int c = idx >> 3, ch = idx & 7;
    s16x8 o;
    #pragma unroll
    for(int e=0;e<8;e++) o[e] = T[ch*8+e][c];
    *(s16x8*)(WoT + (long)(c0+c)*896 + k0 + ch*8) = o;
  }
}

__global__ void rope_table_kernel(const int* __restrict__ pos, float* __restrict__ ct,
                                  float* __restrict__ st){
  int t = blockIdx.x*256 + threadIdx.x;
  if(t >= NROW*32) return;
  int i = t & 31, rn = t >> 5;
  float p = (float)pos[rn];
  float inv = powf(1.0e6f, -(float)i * (1.0f/32.0f));
  float a = p * inv;
  ct[t] = cosf(a);
  st[t] = sinf(a);
}

// ---------------- K/V fragment packing ----------------
// Emits Kp/Vp in per-lane fragment order so every in-loop attention load is
// 64 lanes x 16B contiguous (kills the 32-line-per-instruction gathers).
// Kp[bh][j][f=kt*4+ks][l] = K[bh][j*64+kt*32+(l&31)][16ks+8*(l>>5) .. +8)
// Vp[bh][j][f=mt*4+ss][l] : shorts[e]  = V[bh][j*64+16ss+4*(l>>5)+e  ][mt*32+(l&31)]
//                           shorts[4+e]= V[bh][j*64+16ss+4*(l>>5)+8+e][mt*32+(l&31)]

__global__ __launch_bounds__(256)
void pack_kv_kernel(const short* __restrict__ Kb, const short* __restrict__ Vb,
                    short* __restrict__ Kp, short* __restrict__ Vp){
  __shared__ short Kl[64][72];
  __shared__ short Vl[64][72];   // Vl[n][d]
  int j  = blockIdx.x;      // 0..31
  int bh = blockIdx.y;      // 0..3
  int tid = threadIdx.x;
  #pragma unroll
  for(int it=0; it<2; ++it){
    int idx = it*256 + tid;       // 0..511
    int r = idx >> 3, c0 = (idx & 7)*8;
    *(s16x8*)&Kl[r][c0] = *(const s16x8*)(Kb + ((long)bh*NSEQ + j*64 + r)*HD + c0);
    *(s16x8*)&Vl[r][c0] = *(const s16x8*)(Vb + ((long)bh*NSEQ + j*64 + r)*HD + c0);
  }
  __syncthreads();
  long base = ((long)bh*32 + j)*4096;
  #pragma unroll
  for(int it=0; it<2; ++it){
    int c = it*256 + tid;         // fragment-chunk 0..511
    int f = c >> 6, l = c & 63;
    int kt = f >> 2, ks = f & 3, h = l >> 5, r5 = l & 31;
    *(s16x8*)(Kp + base + f*512 + l*8) = *(const s16x8*)&Kl[kt*32 + r5][16*ks + 8*h];
    s16x8 o;
    #pragma unroll
    for(int e=0;e<4;e++){
      o[e]   = Vl[16*ks + 4*h + e    ][kt*32 + r5];
      o[4+e] = Vl[16*ks + 4*h + 8 + e][kt*32 + r5];
    }
    *(s16x8*)(Vp + base + f*512 + l*8) = o;
  }
}

// ---------------- GEMM (bf16 MFMA, reg-staged LDS double-buffer) ----------------
// EPI=0: QKVG epilogue (Q pre-scaled by QSC), EPI=1: plain f32 out
// NOTE: every loop touching acc[][] MUST be #pragma unroll'd (rule #20).

template<int EPI>
__global__ __launch_bounds__(256)
void gemm_kernel(const short* __restrict__ A, const short* __restrict__ Bt,
                 int Ncols, int K,
                 const float* __restrict__ bq, const float* __restrict__ bk,
                 const float* __restrict__ bv,
                 const float* __restrict__ ct, const float* __restrict__ st,
                 short* __restrict__ Qb, short* __restrict__ Kb, short* __restrict__ Vb,
                 short* __restrict__ gateb, float* __restrict__ outp)
{
  __shared__ short As[2][128*PS];
  __shared__ short Bs[2][128*PS];

  int tid = threadIdx.x;
  int w = tid >> 6, l = tid & 63;
  int wm = w >> 1, wn = w & 1;
  int row0 = blockIdx.y*128;
  int col0 = blockIdx.x*128;
  int lo = l & 15, hi = l >> 4;

  const short* A0 = A  + (long)row0*K;
  const short* B0 = Bt + (long)col0*K;

  f32x4 acc[4][4];
  #pragma unroll
  for(int mi=0;mi<4;mi++)
    #pragma unroll
    for(int ni=0;ni<4;ni++) acc[mi][ni] = (f32x4){0.f,0.f,0.f,0.f};

  int srow = tid >> 2;
  int scol = (tid & 3)*8;

  s16x8 ra[2], rb[2];
  auto gload = [&](int k0){
    #pragma unroll
    for(int i=0;i<2;i++){
      int row = i*64 + srow;
      ra[i] = *(const s16x8*)(A0 + (long)row*K + k0 + scol);
      rb[i] = *(const s16x8*)(B0 + (long)row*K + k0 + scol);
    }
  };
  auto swrite = [&](int buf){
    #pragma unroll
    for(int i=0;i<2;i++){
      int row = i*64 + srow;
      *(s16x8*)&As[buf][row*PS + scol] = ra[i];
      *(s16x8*)&Bs[buf][row*PS + scol] = rb[i];
    }
  };

  gload(0);
  swrite(0);

  int NIT = K >> 5;
  int cur = 0;
  for(int it=0; it<NIT; ++it){
    __syncthreads();
    if(it+1 < NIT) gload((it+1)*32);

    s16x8 af[4], bf[4];
    #pragma unroll
    for(int mi=0;mi<4;mi++) af[mi] = *(const s16x8*)&As[cur][(wm*64 + 16*mi + lo)*PS + 8*hi];
    #pragma unroll
    for(int ni=0;ni<4;ni++) bf[ni] = *(const s16x8*)&Bs[cur][(wn*64 + 16*ni + lo)*PS + 8*hi];
    #pragma unroll
    for(int mi=0;mi<4;mi++)
      #pragma unroll
      for(int ni=0;ni<4;ni++)
        acc[mi][ni] = __builtin_amdgcn_mfma_f32_16x16x32_bf16(af[mi], bf[ni], acc[mi][ni], 0,0,0);

    if(it+1 < NIT) swrite(cur^1);
    cur ^= 1;
  }

  if(EPI == 1){
    #pragma unroll
    for(int mi=0;mi<4;mi++)
      #pragma unroll
      for(int ni=0;ni<4;ni++)
        #pragma unroll
        for(int rg=0;rg<4;rg++){
          int r = row0 + wm*64 + 16*mi + 4*hi + rg;
          int c = col0 + wn*64 + lo + 16*ni;
          outp[(long)r*Ncols + c] = acc[mi][ni][rg];
        }
  } else {
    int wcol0 = col0 + wn*64;
    int region = (wcol0 < 896) ? 0 : (wcol0 < 1024) ? 1 : (wcol0 < 1152) ? 2 : 3;
    #pragma unroll
    for(int mi=0;mi<4;mi++){
      #pragma unroll
      for(int rg=0;rg<4;rg++){
        int r = row0 + wm*64 + 16*mi + 4*hi + rg;
        int b = r >> 11, n = r & 2047;
        if(region <= 1){
          #pragma unroll
          for(int ni=0;ni<2;ni++){
            int c  = wcol0 + lo + 16*ni;
            int cb = (region==0) ? c : (c-896);
            int hh = cb >> 6, dlo = cb & 63;
            float bl = (region==0) ? bq[c]    : bk[cb];
            float bh = (region==0) ? bq[c+32] : bk[cb+32];
            float ylo = acc[mi][ni  ][rg] + bl;
            float yhi = acc[mi][ni+2][rg] + bh;
            float cs = ct[r*32 + dlo];
            float sn = st[r*32 + dlo];
            float olo = ylo*cs - yhi*sn;
            float ohi = yhi*cs + ylo*sn;
            if(region==0){
              long base = ((long)(b*NHQ + hh)*NSEQ + n)*HD;
              Qb[base + dlo]      = f2bf(olo*QSC);
              Qb[base + dlo + 32] = f2bf(ohi*QSC);
            } else {
              long base = ((long)(b*NHKV + hh)*NSEQ + n)*HD;
              Kb[base + dlo]      = f2bf(olo);
              Kb[base + dlo + 32] = f2bf(ohi);
            }
          }
        } else if(region == 2){
          #pragma unroll
          for(int ni=0;ni<4;ni++){
            int c = wcol0 + lo + 16*ni;
            int cv = c - 1024;
            int hh = cv >> 6, d = cv & 63;
            float y = acc[mi][ni][rg] + bv[cv];
            Vb[((long)(b*NHKV + hh)*NSEQ + n)*HD + d] = f2bf(y);
          }
        } else {
          #pragma unroll
          for(int ni=0;ni<4;ni++){
            int c = wcol0 + lo + 16*ni;
            int cg = c - 1152;
            float y = acc[mi][ni][rg];
            gateb[(long)r*NHID + cg] = f2bf(1.0f/(1.0f + __expf(-y)));
          }
        }
      }
    }
  }
}

// ---------------- split-K flash attention, 7 GQA heads per block ----------------
// EXACT R9-verified stream (54.6us, absmax 3.9e-3). Coalesced packed-fragment
// loads; K prefetched one group ahead; V loaded at top of step. Do NOT
// restructure this loop without a verified A/B — two scheduling rewrites
// (R6, R10) both produced wrong values near the VGPR limit.

__global__ __launch_bounds__(448)
void attn3_kernel(const short* __restrict__ Qb, const short* __restrict__ Kp,
                  const short* __restrict__ Vp, const short* __restrict__ gateb,
                  short* __restrict__ Og, float* __restrict__ Pbuf)
{
  int tid = threadIdx.x;
  int l = tid & 63;
  int q5 = l & 31, h = l >> 5;
  int hg = tid >> 6;              // wave id = head-in-group 0..6

  int s = blockIdx.x;             // 0..159 chunk slot
  int kvb = blockIdx.y;           // 0..3 = (b,kv)
  int b = kvb >> 1, kv = kvb & 1;
  int hq = kv*7 + hg;
  int head = kvb*7 + hg;          // Pbuf head index (matches combine decode)

  int t, ci, nc;
  if(s < 16){ t = s; ci = 0; nc = 1; }
  else if(s < 48){ int r = s-16; t = 16 + (r>>1); ci = r & 1; nc = 2; }
  else if(s < 96){ int r = s-48; t = 32 + r/3; ci = r - (r/3)*3; nc = 3; }
  else { int r = s-96; t = 48 + (r>>2); ci = r & 3; nc = 4; }

  int qg = t*32 + q5;
  int jcausal = (t*32 + 31) >> 6;           // diagonal 64-key group; in last chunk
  int j0 = ci*8;
  int j1 = (ci == nc-1) ? jcausal : (j0 + 7);

  const short* qrow = Qb + ((long)(b*NHQ + hq)*NSEQ + t*32 + q5)*HD;
  s16x8 qf[4];
  #pragma unroll
  for(int ks=0; ks<4; ++ks) qf[ks] = *(const s16x8*)(qrow + 16*ks + 8*h);

  const short* kpb = Kp + (long)kvb*32*4096 + l*8;
  const short* vpb = Vp + (long)kvb*32*4096 + l*8;

  f32x16 oT[2];
  #pragma unroll
  for(int mt=0; mt<2; ++mt)
    #pragma unroll
    for(int rg=0; rg<16; ++rg) oT[mt][rg] = 0.f;
  float m = -__builtin_inff(), lsum = 0.f;

  // preload K group j0 (coalesced fragment reads)
  s16x8 kf[2][4];
  #pragma unroll
  for(int kt=0; kt<2; ++kt)
    #pragma unroll
    for(int ks=0; ks<4; ++ks)
      kf[kt][ks] = *(const s16x8*)(kpb + (long)j0*4096 + (kt*4+ks)*512);

  for(int j=j0; j<=j1; ++j){
    // V fragments (coalesced)
    s16x8 vf[2][4];
    #pragma unroll
    for(int mt=0; mt<2; ++mt)
      #pragma unroll
      for(int ss=0; ss<4; ++ss)
        vf[mt][ss] = *(const s16x8*)(vpb + (long)j*4096 + (mt*4+ss)*512);

    // S^T = K * Q^T (softmax scale pre-folded into Q, log2 domain)
    f32x16 s2[2];
    #pragma unroll
    for(int kt=0; kt<2; ++kt)
      #pragma unroll
      for(int rg=0; rg<16; ++rg) s2[kt][rg] = 0.f;
    #pragma unroll
    for(int kt=0; kt<2; ++kt)
      #pragma unroll
      for(int ks=0; ks<4; ++ks)
        s2[kt] = __builtin_amdgcn_mfma_f32_32x32x16_bf16(kf[kt][ks], qf[ks], s2[kt], 0,0,0);

    // prefetch next K group while softmax+PV run
    int jn = (j < j1) ? j+1 : j;
    s16x8 kn[2][4];
    #pragma unroll
    for(int kt=0; kt<2; ++kt)
      #pragma unroll
      for(int ks=0; ks<4; ++ks)
        kn[kt][ks] = *(const s16x8*)(kpb + (long)jn*4096 + (kt*4+ks)*512);

    // causal mask (diagonal group only). key row = (rg&3)+8*(rg>>2)+4h
    if(j == jcausal){
      #pragma unroll
      for(int kt=0; kt<2; ++kt)
        #pragma unroll
        for(int rg=0; rg<16; ++rg){
          int kl = j*64 + kt*32 + (rg&3) + 8*(rg>>2) + 4*h;
          if(kl > qg) s2[kt][rg] = -__builtin_inff();
        }
    }

    // row-max: in-lane tree + 1 shuffle across h
    float mA[8];
    #pragma unroll
    for(int w8=0; w8<8; ++w8)
      mA[w8] = fmaxf(fmaxf(s2[0][w8], s2[0][w8+8]), fmaxf(s2[1][w8], s2[1][w8+8]));
    float mx = fmaxf(fmaxf(fmaxf(mA[0],mA[1]), fmaxf(mA[2],mA[3])),
                     fmaxf(fmaxf(mA[4],mA[5]), fmaxf(mA[6],mA[7])));
    mx = fmaxf(mx, __shfl_xor(mx, 32, 64));

    // defer-max: only rescale when max grew by > 8 (log2 domain, P <= 256)
    if(__any(mx > m + 8.0f)){
      float mn = fmaxf(m, mx);
      float fac = exp2f(m - mn);
      m = mn;
      lsum *= fac;
      #pragma unroll
      for(int mt=0; mt<2; ++mt)
        #pragma unroll
        for(int rg=0; rg<16; ++rg) oT[mt][rg] *= fac;
    }

    // exp + row-sum (tree + 1 shuffle)
    #pragma unroll
    for(int kt=0; kt<2; ++kt)
      #pragma unroll
      for(int rg=0; rg<16; ++rg) s2[kt][rg] = exp2f(s2[kt][rg] - m);
    float sA[8];
    #pragma unroll
    for(int w8=0; w8<8; ++w8)
      sA[w8] = (s2[0][w8] + s2[0][w8+8]) + (s2[1][w8] + s2[1][w8+8]);
    float rs = ((sA[0]+sA[1]) + (sA[2]+sA[3])) + ((sA[4]+sA[5]) + (sA[6]+sA[7]));
    rs += __shfl_xor(rs, 32, 64);
    lsum += rs;

    // pack P to bf16 pairs: pd[kt][w] = {p[2w] lo, p[2w+1] hi}
    int pd[2][8];
    #pragma unroll
    for(int kt=0; kt<2; ++kt)
      #pragma unroll
      for(int w8=0; w8<8; ++w8)
        asm("v_cvt_pk_bf16_f32 %0, %1, %2"
            : "=v"(pd[kt][w8]) : "v"(s2[kt][2*w8]), "v"(s2[kt][2*w8+1]));

    // PV: O^T += V^T * P^T ; B-frag for step ss = pd[ss>>1][4*(ss&1) .. +3]
    #pragma unroll
    for(int ss=0; ss<4; ++ss){
      union { int i4[4]; s16x8 v8; } pf;
      #pragma unroll
      for(int e=0; e<4; ++e) pf.i4[e] = pd[ss>>1][4*(ss&1) + e];
      #pragma unroll
      for(int mt=0; mt<2; ++mt)
        oT[mt] = __builtin_amdgcn_mfma_f32_32x32x16_bf16(vf[mt][ss], pf.v8, oT[mt], 0,0,0);
    }

    // roll K prefetch
    #pragma unroll
    for(int kt=0; kt<2; ++kt)
      #pragma unroll
      for(int ks=0; ks<4; ++ks) kf[kt][ks] = kn[kt][ks];
  }

  if(nc == 1){
    float inv = 1.0f/lsum;
    long obase = ((long)(b*NSEQ + t*32 + q5))*NHID + hq*HD;
    #pragma unroll
    for(int mt=0; mt<2; ++mt)
      #pragma unroll
      for(int rq=0; rq<4; ++rq){
        int d0 = mt*32 + 8*rq + 4*h;
        s16x4 g4 = *(const s16x4*)(gateb + obase + d0);
        s16x4 o4;
        #pragma unroll
        for(int e=0; e<4; ++e)
          o4[e] = f2bf(oT[mt][4*rq + e]*inv*bf2f((unsigned short)g4[e]));
        *(s16x4*)(Og + obase + d0) = o4;
      }
  } else {
    int g = t >> 4;
    int poff = (g==1) ? (t-16)*2 : (g==2) ? 32 + (t-32)*3 : 80 + (t-48)*4;
    float* pb = Pbuf + ((long)head*144 + poff + ci)*2112;
    #pragma unroll
    for(int mt=0; mt<2; ++mt)
      #pragma unroll
      for(int rg=0; rg<16; ++rg){
        int d = mt*32 + (rg&3) + 8*(rg>>2) + 4*h;
        pb[q5*64 + d] = oT[mt][rg];
      }
    if(h == 0){
      pb[2048 + q5] = m;
      pb[2080 + q5] = lsum;
    }
  }
}

// ---------------- split-K combine (t >= 16 tiles) ----------------

__global__ __launch_bounds__(64)
void attn_combine_kernel(const float* __restrict__ Pbuf, const short* __restrict__ gateb,
                         short* __restrict__ Og)
{
  int t = 16 + blockIdx.x;        // 16..63
  int head = blockIdx.y;          // 0..27
  int hg = head % 7; int kvb = head / 7; int b = kvb >> 1; int kv = kvb & 1;
  int hq = kv*7 + hg;
  int nc = (t >> 4) + 1;          // 2..4
  int g = t >> 4;
  int poff = (g==1) ? (t-16)*2 : (g==2) ? 32 + (t-32)*3 : 80 + (t-48)*4;
  const float* pb0 = Pbuf + ((long)head*144 + poff)*2112;

  int l = threadIdx.x;
  int q5 = l & 31;
  int d0 = (l >> 5)*32;

  float ms[4];
  float M = -__builtin_inff();
  #pragma unroll
  for(int i=0;i<4;i++){
    ms[i] = (i < nc) ? pb0[i*2112 + 2048 + q5] : -__builtin_inff();
    M = fmaxf(M, ms[i]);
  }
  float L = 0.f;
  f32x4 Oa[8];
  #pragma unroll
  for(int c=0;c<8;c++) Oa[c] = (f32x4){0.f,0.f,0.f,0.f};
  #pragma unroll
  for(int i=0;i<4;i++){
    if(i < nc){
      float fac = exp2f(ms[i] - M);
      L += pb0[i*2112 + 2080 + q5] * fac;
      const float* po = pb0 + i*2112 + q5*64 + d0;
      #pragma unroll
      for(int c=0;c<8;c++){
        f32x4 v = *(const f32x4*)(po + 4*c);
        #pragma unroll
        for(int e=0;e<4;e++) Oa[c][e] += v[e]*fac;
      }
    }
  }
  float inv = 1.0f/L;
  long obase = ((long)(b*NSEQ + t*32 + q5))*NHID + hq*HD + d0;
  #pragma unroll
  for(int c=0;c<8;c++){
    s16x4 g4 = *(const s16x4*)(gateb + obase + 4*c);
    s16x4 o4;
    #pragma unroll
    for(int e=0;e<4;e++)
      o4[e] = f2bf(Oa[c][e]*inv*bf2f((unsigned short)g4[e]));
    *(s16x4*)(Og + obase + 4*c) = o4;
  }
}

// ---------------- launch ----------------

extern "C" void kernel_launch(void* const* d_in, const int* in_sizes, int n_in,
                              void* d_out, int out_size, void* d_ws, size_t ws_size,
                              hipStream_t stream)
{
  const float* hs  = (const float*)d_in[0];
  const int*   pos = (const int*)d_in[1];
  const float* Wq  = (const float*)d_in[2];
  const float* bq  = (const float*)d_in[3];
  const float* Wk  = (const float*)d_in[4];
  const float* bk  = (const float*)d_in[5];
  const float* Wv  = (const float*)d_in[6];
  const float* bv  = (const float*)d_in[7];
  const float* Wg  = (const float*)d_in[8];
  const float* Wo  = (const float*)d_in[9];
  float* out = (float*)d_out;

  char* p = (char*)d_ws;
  short* Xb    = (short*)p; p += (size_t)NROW*NHID*2;
  short* WcatT = (short*)p; p += (size_t)NCAT*NHID*2;
  short* WoT   = (short*)p; p += (size_t)NHID*NHID*2;
  float* ct    = (float*)p; p += (size_t)NROW*32*4;
  float* st    = (float*)p; p += (size_t)NROW*32*4;
  short* Qb    = (short*)p; p += (size_t)NB*NHQ*NSEQ*HD*2;
  short* Kb    = (short*)p; p += (size_t)NB*NHKV*NSEQ*HD*2;
  short* Vb    = (short*)p; p += (size_t)NB*NHKV*NSEQ*HD*2;
  short* Kp    = (short*)p; p += (size_t)4*32*4096*2;     // packed K fragments (1 MB)
  short* Vp    = (short*)p; p += (size_t)4*32*4096*2;     // packed V fragments (1 MB)
  short* gateb = (short*)p; p += (size_t)NROW*NHID*2;
  short* Og    = (short*)p; p += (size_t)NROW*NHID*2;
  float* Pbuf  = (float*)p; p += (size_t)28*144*2112*4;   // 34 MB split-K partials

  pack_x_kernel<<<(NROW*NHID+255)/256, 256, 0, stream>>>(hs, Xb, NROW*NHID);
  pack_wcat_t_kernel<<<dim3(NCAT/64, NHID/64), 256, 0, stream>>>(Wq, Wk, Wv, Wg, WcatT);
  pack_wo_t_kernel<<<dim3(NHID/64, NHID/64), 256, 0, stream>>>(Wo, WoT);
  rope_table_kernel<<<(NROW*32+255)/256, 256, 0, stream>>>(pos, ct, st);

  gemm_kernel<0><<<dim3(NCAT/128, NROW/128), 256, 0, stream>>>(
      Xb, WcatT, NCAT, NHID, bq, bk, bv, ct, st, Qb, Kb, Vb, gateb, nullptr);

  pack_kv_kernel<<<dim3(32, 4), 256, 0, stream>>>(Kb, Vb, Kp, Vp);

  attn3_kernel<<<dim3(160, 4), 448, 0, stream>>>(Qb, Kp, Vp, gateb, Og, Pbuf);
  attn_combine_kernel<<<dim3(48, 28), 64, 0, stream>>>(Pbuf, gateb, Og);

  gemm_kernel<1><<<dim3(NHID/128, NROW/128), 256, 0, stream>>>(
      Og, WoT, NHID, NHID, nullptr, nullptr, nullptr, nullptr, nullptr,
      nullptr, nullptr, nullptr, nullptr, out);
}

// Round 13
// 133.385 us; speedup vs baseline: 1.6485x; 1.0120x over previous
//
#include <hip/hip_runtime.h>
#include <hip/hip_bf16.h>

typedef short s16x4 __attribute__((ext_vector_type(4)));
typedef short s16x8 __attribute__((ext_vector_type(8)));
typedef float f32x4 __attribute__((ext_vector_type(4)));
typedef float f32x16 __attribute__((ext_vector_type(16)));

#define NB 2
#define NSEQ 2048
#define NHID 896
#define NHQ 14
#define NHKV 2
#define HD 64
#define NROW (NB*NSEQ)     // 4096
#define NCAT 2048          // 896 Q | 128 K | 128 V | 896 gate
#define PS 40              // padded LDS row stride in shorts (80B, 16B-aligned)
#define QSC 0.18033688011112042f   // (1/8) * log2(e), folded into Q at projection

__device__ __forceinline__ float bf2f(unsigned short s){
  union { float f; unsigned u; } v; v.u = ((unsigned)s) << 16; return v.f;
}
__device__ __forceinline__ short f2bf(float f){
  union { float f; unsigned u; } v; v.f = f;
  unsigned u = v.u + 0x7fffu + ((v.u >> 16) & 1u);
  return (short)(u >> 16);
}

// ---------------- packing kernels ----------------

__global__ void pack_x_kernel(const float* __restrict__ x, short* __restrict__ xb, int n){
  int i = blockIdx.x*256 + threadIdx.x;
  if(i < n) xb[i] = f2bf(x[i]);
}

// LDS-tiled transpose pack: WcatT[c][k] = W_region(k, c), coalesced both sides.
__global__ __launch_bounds__(256)
void pack_wcat_t_kernel(const float* __restrict__ Wq, const float* __restrict__ Wk,
                        const float* __restrict__ Wv, const float* __restrict__ Wg,
                        short* __restrict__ WcatT){
  __shared__ short T[64][73];
  int c0 = blockIdx.x*64, k0 = blockIdx.y*64;
  const float* src; int width, cb;
  if(c0 < 896){ src = Wq; width = 896; cb = c0; }
  else if(c0 < 1024){ src = Wk; width = 128; cb = c0-896; }
  else if(c0 < 1152){ src = Wv; width = 128; cb = c0-1024; }
  else { src = Wg; width = 896; cb = c0-1152; }
  int tid = threadIdx.x;
  #pragma unroll
  for(int it=0; it<4; ++it){
    int idx = it*256 + tid;           // 0..1023
    int r = idx >> 4, q = idx & 15;   // r = k-local, q = float4 chunk of c
    f32x4 v = *(const f32x4*)(src + (long)(k0+r)*width + cb + q*4);
    #pragma unroll
    for(int e=0;e<4;e++) T[r][q*4+e] = f2bf(v[e]);
  }
  __syncthreads();
  #pragma unroll
  for(int it=0; it<2; ++it){
    int idx = it*256 + tid;           // 0..511
    int c = idx >> 3, ch = idx & 7;
    s16x8 o;
    #pragma unroll
    for(int e=0;e<8;e++) o[e] = T[ch*8+e][c];
    *(s16x8*)(WcatT + (long)(c0+c)*NHID + k0 + ch*8) = o;
  }
}

__global__ __launch_bounds__(256)
void pack_wo_t_kernel(const float* __restrict__ Wo, short* __restrict__ WoT){
  __shared__ short T[64][73];
  int c0 = blockIdx.x*64, k0 = blockIdx.y*64;
  int tid = threadIdx.x;
  #pragma unroll
  for(int it=0; it<4; ++it){
    int idx = it*256 + tid;
    int r = idx >> 4, q = idx & 15;
    f32x4 v = *(const f32x4*)(Wo + (long)(k0+r)*896 + c0 + q*4);
    #pragma unroll
    for(int e=0;e<4;e++) T[r][q*4+e] = f2bf(v[e]);
  }
  __syncthreads();
  #pragma unroll
  for(int it=0; it<2; ++it){
    int idx = it*256 + tid;
    int c = idx >> 3, ch = idx & 7;
    s16x8 o;
    #pragma unroll
    for(int e=0;e<8;e++) o[e] = T[ch*8+e][c];
    *(s16x8*)(WoT + (long)(c0+c)*896 + k0 + ch*8) = o;
  }
}

__global__ void rope_table_kernel(const int* __restrict__ pos, float* __restrict__ ct,
                                  float* __restrict__ st){
  int t = blockIdx.x*256 + threadIdx.x;
  if(t >= NROW*32) return;
  int i = t & 31, rn = t >> 5;
  float p = (float)pos[rn];
  float inv = powf(1.0e6f, -(float)i * (1.0f/32.0f));
  float a = p * inv;
  ct[t] = cosf(a);
  st[t] = sinf(a);
}

// ---------------- K/V fragment packing ----------------
// Kp[bh][j][f=kt*4+ks][l] = K[bh][j*64+kt*32+(l&31)][16ks+8*(l>>5) .. +8)
// Vp[bh][j][f=mt*4+ss][l] : shorts[e]  = V[bh][j*64+16ss+4*(l>>5)+e  ][mt*32+(l&31)]
//                           shorts[4+e]= V[bh][j*64+16ss+4*(l>>5)+8+e][mt*32+(l&31)]

__global__ __launch_bounds__(256)
void pack_kv_kernel(const short* __restrict__ Kb, const short* __restrict__ Vb,
                    short* __restrict__ Kp, short* __restrict__ Vp){
  __shared__ short Kl[64][72];
  __shared__ short Vl[64][72];   // Vl[n][d]
  int j  = blockIdx.x;      // 0..31
  int bh = blockIdx.y;      // 0..3
  int tid = threadIdx.x;
  #pragma unroll
  for(int it=0; it<2; ++it){
    int idx = it*256 + tid;       // 0..511
    int r = idx >> 3, c0 = (idx & 7)*8;
    *(s16x8*)&Kl[r][c0] = *(const s16x8*)(Kb + ((long)bh*NSEQ + j*64 + r)*HD + c0);
    *(s16x8*)&Vl[r][c0] = *(const s16x8*)(Vb + ((long)bh*NSEQ + j*64 + r)*HD + c0);
  }
  __syncthreads();
  long base = ((long)bh*32 + j)*4096;
  #pragma unroll
  for(int it=0; it<2; ++it){
    int c = it*256 + tid;         // fragment-chunk 0..511
    int f = c >> 6, l = c & 63;
    int kt = f >> 2, ks = f & 3, h = l >> 5, r5 = l & 31;
    *(s16x8*)(Kp + base + f*512 + l*8) = *(const s16x8*)&Kl[kt*32 + r5][16*ks + 8*h];
    s16x8 o;
    #pragma unroll
    for(int e=0;e<4;e++){
      o[e]   = Vl[16*ks + 4*h + e    ][kt*32 + r5];
      o[4+e] = Vl[16*ks + 4*h + 8 + e][kt*32 + r5];
    }
    *(s16x8*)(Vp + base + f*512 + l*8) = o;
  }
}

// ---------------- GEMM (bf16 MFMA, reg-staged LDS double-buffer) ----------------
// EPI=0: QKVG epilogue (Q pre-scaled by QSC), EPI=1: plain f32 out
// XCD-aware block swizzle (grid size divisible by 8 for both uses: 512, 224).
// NOTE: every loop touching acc[][] MUST be #pragma unroll'd (rule #20).

template<int EPI>
__global__ __launch_bounds__(256)
void gemm_kernel(const short* __restrict__ A, const short* __restrict__ Bt,
                 int Ncols, int K,
                 const float* __restrict__ bq, const float* __restrict__ bk,
                 const float* __restrict__ bv,
                 const float* __restrict__ ct, const float* __restrict__ st,
                 short* __restrict__ Qb, short* __restrict__ Kb, short* __restrict__ Vb,
                 short* __restrict__ gateb, float* __restrict__ outp)
{
  __shared__ short As[2][128*PS];
  __shared__ short Bs[2][128*PS];

  int tid = threadIdx.x;
  int w = tid >> 6, l = tid & 63;
  int wm = w >> 1, wn = w & 1;

  // XCD swizzle: consecutive swizzled ids land on the same XCD.
  int bid = blockIdx.y * gridDim.x + blockIdx.x;
  int cpx = (gridDim.x * gridDim.y) >> 3;
  int swz = (bid & 7)*cpx + (bid >> 3);
  int bx = swz % gridDim.x, by = swz / gridDim.x;

  int row0 = by*128;
  int col0 = bx*128;
  int lo = l & 15, hi = l >> 4;

  const short* A0 = A  + (long)row0*K;
  const short* B0 = Bt + (long)col0*K;

  f32x4 acc[4][4];
  #pragma unroll
  for(int mi=0;mi<4;mi++)
    #pragma unroll
    for(int ni=0;ni<4;ni++) acc[mi][ni] = (f32x4){0.f,0.f,0.f,0.f};

  int srow = tid >> 2;
  int scol = (tid & 3)*8;

  s16x8 ra[2], rb[2];
  auto gload = [&](int k0){
    #pragma unroll
    for(int i=0;i<2;i++){
      int row = i*64 + srow;
      ra[i] = *(const s16x8*)(A0 + (long)row*K + k0 + scol);
      rb[i] = *(const s16x8*)(B0 + (long)row*K + k0 + scol);
    }
  };
  auto swrite = [&](int buf){
    #pragma unroll
    for(int i=0;i<2;i++){
      int row = i*64 + srow;
      *(s16x8*)&As[buf][row*PS + scol] = ra[i];
      *(s16x8*)&Bs[buf][row*PS + scol] = rb[i];
    }
  };

  gload(0);
  swrite(0);

  int NIT = K >> 5;
  int cur = 0;
  for(int it=0; it<NIT; ++it){
    __syncthreads();
    if(it+1 < NIT) gload((it+1)*32);

    s16x8 af[4], bf[4];
    #pragma unroll
    for(int mi=0;mi<4;mi++) af[mi] = *(const s16x8*)&As[cur][(wm*64 + 16*mi + lo)*PS + 8*hi];
    #pragma unroll
    for(int ni=0;ni<4;ni++) bf[ni] = *(const s16x8*)&Bs[cur][(wn*64 + 16*ni + lo)*PS + 8*hi];
    #pragma unroll
    for(int mi=0;mi<4;mi++)
      #pragma unroll
      for(int ni=0;ni<4;ni++)
        acc[mi][ni] = __builtin_amdgcn_mfma_f32_16x16x32_bf16(af[mi], bf[ni], acc[mi][ni], 0,0,0);

    if(it+1 < NIT) swrite(cur^1);
    cur ^= 1;
  }

  if(EPI == 1){
    #pragma unroll
    for(int mi=0;mi<4;mi++)
      #pragma unroll
      for(int ni=0;ni<4;ni++)
        #pragma unroll
        for(int rg=0;rg<4;rg++){
          int r = row0 + wm*64 + 16*mi + 4*hi + rg;
          int c = col0 + wn*64 + lo + 16*ni;
          outp[(long)r*Ncols + c] = acc[mi][ni][rg];
        }
  } else {
    int wcol0 = col0 + wn*64;
    int region = (wcol0 < 896) ? 0 : (wcol0 < 1024) ? 1 : (wcol0 < 1152) ? 2 : 3;
    #pragma unroll
    for(int mi=0;mi<4;mi++){
      #pragma unroll
      for(int rg=0;rg<4;rg++){
        int r = row0 + wm*64 + 16*mi + 4*hi + rg;
        int b = r >> 11, n = r & 2047;
        if(region <= 1){
          #pragma unroll
          for(int ni=0;ni<2;ni++){
            int c  = wcol0 + lo + 16*ni;
            int cb = (region==0) ? c : (c-896);
            int hh = cb >> 6, dlo = cb & 63;
            float bl = (region==0) ? bq[c]    : bk[cb];
            float bh = (region==0) ? bq[c+32] : bk[cb+32];
            float ylo = acc[mi][ni  ][rg] + bl;
            float yhi = acc[mi][ni+2][rg] + bh;
            float cs = ct[r*32 + dlo];
            float sn = st[r*32 + dlo];
            float olo = ylo*cs - yhi*sn;
            float ohi = yhi*cs + ylo*sn;
            if(region==0){
              long base = ((long)(b*NHQ + hh)*NSEQ + n)*HD;
              Qb[base + dlo]      = f2bf(olo*QSC);
              Qb[base + dlo + 32] = f2bf(ohi*QSC);
            } else {
              long base = ((long)(b*NHKV + hh)*NSEQ + n)*HD;
              Kb[base + dlo]      = f2bf(olo);
              Kb[base + dlo + 32] = f2bf(ohi);
            }
          }
        } else if(region == 2){
          #pragma unroll
          for(int ni=0;ni<4;ni++){
            int c = wcol0 + lo + 16*ni;
            int cv = c - 1024;
            int hh = cv >> 6, d = cv & 63;
            float y = acc[mi][ni][rg] + bv[cv];
            Vb[((long)(b*NHKV + hh)*NSEQ + n)*HD + d] = f2bf(y);
          }
        } else {
          #pragma unroll
          for(int ni=0;ni<4;ni++){
            int c = wcol0 + lo + 16*ni;
            int cg = c - 1152;
            float y = acc[mi][ni][rg];
            gateb[(long)r*NHID + cg] = f2bf(1.0f/(1.0f + __expf(-y)));
          }
        }
      }
    }
  }
}

// ---------------- split-K flash attention, 7 GQA heads per block ----------------
// EXACT R9-verified stream (54.6us, absmax 3.9e-3), passed R9+R11. FROZEN:
// three inner-loop restructures (R6 lambda, R10 V-dbuf, R12 LDS-stage) all
// produced wrong values — do not touch this loop. Only the launch-order
// mapping (LPT, s descending) differs from R11; that is outside the loop.

__global__ __launch_bounds__(448)
void attn3_kernel(const short* __restrict__ Qb, const short* __restrict__ Kp,
                  const short* __restrict__ Vp, const short* __restrict__ gateb,
                  short* __restrict__ Og, float* __restrict__ Pbuf)
{
  int tid = threadIdx.x;
  int l = tid & 63;
  int q5 = l & 31, h = l >> 5;
  int hg = tid >> 6;              // wave id = head-in-group 0..6

  int s = 159 - blockIdx.x;       // LPT: longest chunks dispatch first
  int kvb = blockIdx.y;           // 0..3 = (b,kv)
  int b = kvb >> 1, kv = kvb & 1;
  int hq = kv*7 + hg;
  int head = kvb*7 + hg;          // Pbuf head index (matches combine decode)

  int t, ci, nc;
  if(s < 16){ t = s; ci = 0; nc = 1; }
  else if(s < 48){ int r = s-16; t = 16 + (r>>1); ci = r & 1; nc = 2; }
  else if(s < 96){ int r = s-48; t = 32 + r/3; ci = r - (r/3)*3; nc = 3; }
  else { int r = s-96; t = 48 + (r>>2); ci = r & 3; nc = 4; }

  int qg = t*32 + q5;
  int jcausal = (t*32 + 31) >> 6;           // diagonal 64-key group; in last chunk
  int j0 = ci*8;
  int j1 = (ci == nc-1) ? jcausal : (j0 + 7);

  const short* qrow = Qb + ((long)(b*NHQ + hq)*NSEQ + t*32 + q5)*HD;
  s16x8 qf[4];
  #pragma unroll
  for(int ks=0; ks<4; ++ks) qf[ks] = *(const s16x8*)(qrow + 16*ks + 8*h);

  const short* kpb = Kp + (long)kvb*32*4096 + l*8;
  const short* vpb = Vp + (long)kvb*32*4096 + l*8;

  f32x16 oT[2];
  #pragma unroll
  for(int mt=0; mt<2; ++mt)
    #pragma unroll
    for(int rg=0; rg<16; ++rg) oT[mt][rg] = 0.f;
  float m = -__builtin_inff(), lsum = 0.f;

  // preload K group j0 (coalesced fragment reads)
  s16x8 kf[2][4];
  #pragma unroll
  for(int kt=0; kt<2; ++kt)
    #pragma unroll
    for(int ks=0; ks<4; ++ks)
      kf[kt][ks] = *(const s16x8*)(kpb + (long)j0*4096 + (kt*4+ks)*512);

  for(int j=j0; j<=j1; ++j){
    // V fragments (coalesced)
    s16x8 vf[2][4];
    #pragma unroll
    for(int mt=0; mt<2; ++mt)
      #pragma unroll
      for(int ss=0; ss<4; ++ss)
        vf[mt][ss] = *(const s16x8*)(vpb + (long)j*4096 + (mt*4+ss)*512);

    // S^T = K * Q^T (softmax scale pre-folded into Q, log2 domain)
    f32x16 s2[2];
    #pragma unroll
    for(int kt=0; kt<2; ++kt)
      #pragma unroll
      for(int rg=0; rg<16; ++rg) s2[kt][rg] = 0.f;
    #pragma unroll
    for(int kt=0; kt<2; ++kt)
      #pragma unroll
      for(int ks=0; ks<4; ++ks)
        s2[kt] = __builtin_amdgcn_mfma_f32_32x32x16_bf16(kf[kt][ks], qf[ks], s2[kt], 0,0,0);

    // prefetch next K group while softmax+PV run
    int jn = (j < j1) ? j+1 : j;
    s16x8 kn[2][4];
    #pragma unroll
    for(int kt=0; kt<2; ++kt)
      #pragma unroll
      for(int ks=0; ks<4; ++ks)
        kn[kt][ks] = *(const s16x8*)(kpb + (long)jn*4096 + (kt*4+ks)*512);

    // causal mask (diagonal group only). key row = (rg&3)+8*(rg>>2)+4h
    if(j == jcausal){
      #pragma unroll
      for(int kt=0; kt<2; ++kt)
        #pragma unroll
        for(int rg=0; rg<16; ++rg){
          int kl = j*64 + kt*32 + (rg&3) + 8*(rg>>2) + 4*h;
          if(kl > qg) s2[kt][rg] = -__builtin_inff();
        }
    }

    // row-max: in-lane tree + 1 shuffle across h
    float mA[8];
    #pragma unroll
    for(int w8=0; w8<8; ++w8)
      mA[w8] = fmaxf(fmaxf(s2[0][w8], s2[0][w8+8]), fmaxf(s2[1][w8], s2[1][w8+8]));
    float mx = fmaxf(fmaxf(fmaxf(mA[0],mA[1]), fmaxf(mA[2],mA[3])),
                     fmaxf(fmaxf(mA[4],mA[5]), fmaxf(mA[6],mA[7])));
    mx = fmaxf(mx, __shfl_xor(mx, 32, 64));

    // defer-max: only rescale when max grew by > 8 (log2 domain, P <= 256)
    if(__any(mx > m + 8.0f)){
      float mn = fmaxf(m, mx);
      float fac = exp2f(m - mn);
      m = mn;
      lsum *= fac;
      #pragma unroll
      for(int mt=0; mt<2; ++mt)
        #pragma unroll
        for(int rg=0; rg<16; ++rg) oT[mt][rg] *= fac;
    }

    // exp + row-sum (tree + 1 shuffle)
    #pragma unroll
    for(int kt=0; kt<2; ++kt)
      #pragma unroll
      for(int rg=0; rg<16; ++rg) s2[kt][rg] = exp2f(s2[kt][rg] - m);
    float sA[8];
    #pragma unroll
    for(int w8=0; w8<8; ++w8)
      sA[w8] = (s2[0][w8] + s2[0][w8+8]) + (s2[1][w8] + s2[1][w8+8]);
    float rs = ((sA[0]+sA[1]) + (sA[2]+sA[3])) + ((sA[4]+sA[5]) + (sA[6]+sA[7]));
    rs += __shfl_xor(rs, 32, 64);
    lsum += rs;

    // pack P to bf16 pairs: pd[kt][w] = {p[2w] lo, p[2w+1] hi}
    int pd[2][8];
    #pragma unroll
    for(int kt=0; kt<2; ++kt)
      #pragma unroll
      for(int w8=0; w8<8; ++w8)
        asm("v_cvt_pk_bf16_f32 %0, %1, %2"
            : "=v"(pd[kt][w8]) : "v"(s2[kt][2*w8]), "v"(s2[kt][2*w8+1]));

    // PV: O^T += V^T * P^T ; B-frag for step ss = pd[ss>>1][4*(ss&1) .. +3]
    #pragma unroll
    for(int ss=0; ss<4; ++ss){
      union { int i4[4]; s16x8 v8; } pf;
      #pragma unroll
      for(int e=0; e<4; ++e) pf.i4[e] = pd[ss>>1][4*(ss&1) + e];
      #pragma unroll
      for(int mt=0; mt<2; ++mt)
        oT[mt] = __builtin_amdgcn_mfma_f32_32x32x16_bf16(vf[mt][ss], pf.v8, oT[mt], 0,0,0);
    }

    // roll K prefetch
    #pragma unroll
    for(int kt=0; kt<2; ++kt)
      #pragma unroll
      for(int ks=0; ks<4; ++ks) kf[kt][ks] = kn[kt][ks];
  }

  if(nc == 1){
    float inv = 1.0f/lsum;
    long obase = ((long)(b*NSEQ + t*32 + q5))*NHID + hq*HD;
    #pragma unroll
    for(int mt=0; mt<2; ++mt)
      #pragma unroll
      for(int rq=0; rq<4; ++rq){
        int d0 = mt*32 + 8*rq + 4*h;
        s16x4 g4 = *(const s16x4*)(gateb + obase + d0);
        s16x4 o4;
        #pragma unroll
        for(int e=0; e<4; ++e)
          o4[e] = f2bf(oT[mt][4*rq + e]*inv*bf2f((unsigned short)g4[e]));
        *(s16x4*)(Og + obase + d0) = o4;
      }
  } else {
    int g = t >> 4;
    int poff = (g==1) ? (t-16)*2 : (g==2) ? 32 + (t-32)*3 : 80 + (t-48)*4;
    float* pb = Pbuf + ((long)head*144 + poff + ci)*2112;
    #pragma unroll
    for(int mt=0; mt<2; ++mt)
      #pragma unroll
      for(int rg=0; rg<16; ++rg){
        int d = mt*32 + (rg&3) + 8*(rg>>2) + 4*h;
        pb[q5*64 + d] = oT[mt][rg];
      }
    if(h == 0){
      pb[2048 + q5] = m;
      pb[2080 + q5] = lsum;
    }
  }
}

// ---------------- split-K combine (t >= 16 tiles) ----------------

__global__ __launch_bounds__(64)
void attn_combine_kernel(const float* __restrict__ Pbuf, const short* __restrict__ gateb,
                         short* __restrict__ Og)
{
  int t = 16 + blockIdx.x;        // 16..63
  int head = blockIdx.y;          // 0..27
  int hg = head % 7; int kvb = head / 7; int b = kvb >> 1; int kv = kvb & 1;
  int hq = kv*7 + hg;
  int nc = (t >> 4) + 1;          // 2..4
  int g = t >> 4;
  int poff = (g==1) ? (t-16)*2 : (g==2) ? 32 + (t-32)*3 : 80 + (t-48)*4;
  const float* pb0 = Pbuf + ((long)head*144 + poff)*2112;

  int l = threadIdx.x;
  int q5 = l & 31;
  int d0 = (l >> 5)*32;

  float ms[4];
  float M = -__builtin_inff();
  #pragma unroll
  for(int i=0;i<4;i++){
    ms[i] = (i < nc) ? pb0[i*2112 + 2048 + q5] : -__builtin_inff();
    M = fmaxf(M, ms[i]);
  }
  float L = 0.f;
  f32x4 Oa[8];
  #pragma unroll
  for(int c=0;c<8;c++) Oa[c] = (f32x4){0.f,0.f,0.f,0.f};
  #pragma unroll
  for(int i=0;i<4;i++){
    if(i < nc){
      float fac = exp2f(ms[i] - M);
      L += pb0[i*2112 + 2080 + q5] * fac;
      const float* po = pb0 + i*2112 + q5*64 + d0;
      #pragma unroll
      for(int c=0;c<8;c++){
        f32x4 v = *(const f32x4*)(po + 4*c);
        #pragma unroll
        for(int e=0;e<4;e++) Oa[c][e] += v[e]*fac;
      }
    }
  }
  float inv = 1.0f/L;
  long obase = ((long)(b*NSEQ + t*32 + q5))*NHID + hq*HD + d0;
  #pragma unroll
  for(int c=0;c<8;c++){
    s16x4 g4 = *(const s16x4*)(gateb + obase + 4*c);
    s16x4 o4;
    #pragma unroll
    for(int e=0;e<4;e++)
      o4[e] = f2bf(Oa[c][e]*inv*bf2f((unsigned short)g4[e]));
    *(s16x4*)(Og + obase + 4*c) = o4;
  }
}

// ---------------- launch ----------------

extern "C" void kernel_launch(void* const* d_in, const int* in_sizes, int n_in,
                              void* d_out, int out_size, void* d_ws, size_t ws_size,
                              hipStream_t stream)
{
  const float* hs  = (const float*)d_in[0];
  const int*   pos = (const int*)d_in[1];
  const float* Wq  = (const float*)d_in[2];
  const float* bq  = (const float*)d_in[3];
  const float* Wk  = (const float*)d_in[4];
  const float* bk  = (const float*)d_in[5];
  const float* Wv  = (const float*)d_in[6];
  const float* bv  = (const float*)d_in[7];
  const float* Wg  = (const float*)d_in[8];
  const float* Wo  = (const float*)d_in[9];
  float* out = (float*)d_out;

  char* p = (char*)d_ws;
  short* Xb    = (short*)p; p += (size_t)NROW*NHID*2;
  short* WcatT = (short*)p; p += (size_t)NCAT*NHID*2;
  short* WoT   = (short*)p; p += (size_t)NHID*NHID*2;
  float* ct    = (float*)p; p += (size_t)NROW*32*4;
  float* st    = (float*)p; p += (size_t)NROW*32*4;
  short* Qb    = (short*)p; p += (size_t)NB*NHQ*NSEQ*HD*2;
  short* Kb    = (short*)p; p += (size_t)NB*NHKV*NSEQ*HD*2;
  short* Vb    = (short*)p; p += (size_t)NB*NHKV*NSEQ*HD*2;
  short* Kp    = (short*)p; p += (size_t)4*32*4096*2;     // packed K fragments (1 MB)
  short* Vp    = (short*)p; p += (size_t)4*32*4096*2;     // packed V fragments (1 MB)
  short* gateb = (short*)p; p += (size_t)NROW*NHID*2;
  short* Og    = (short*)p; p += (size_t)NROW*NHID*2;
  float* Pbuf  = (float*)p; p += (size_t)28*144*2112*4;   // 34 MB split-K partials

  pack_x_kernel<<<(NROW*NHID+255)/256, 256, 0, stream>>>(hs, Xb, NROW*NHID);
  pack_wcat_t_kernel<<<dim3(NCAT/64, NHID/64), 256, 0, stream>>>(Wq, Wk, Wv, Wg, WcatT);
  pack_wo_t_kernel<<<dim3(NHID/64, NHID/64), 256, 0, stream>>>(Wo, WoT);
  rope_table_kernel<<<(NROW*32+255)/256, 256, 0, stream>>>(pos, ct, st);

  gemm_kernel<0><<<dim3(NCAT/128, NROW/128), 256, 0, stream>>>(
      Xb, WcatT, NCAT, NHID, bq, bk, bv, ct, st, Qb, Kb, Vb, gateb, nullptr);

  pack_kv_kernel<<<dim3(32, 4), 256, 0, stream>>>(Kb, Vb, Kp, Vp);

  attn3_kernel<<<dim3(160, 4), 448, 0, stream>>>(Qb, Kp, Vp, gateb, Og, Pbuf);
  attn_combine_kernel<<<dim3(48, 28), 64, 0, stream>>>(Pbuf, gateb, Og);

  gemm_kernel<1><<<dim3(NHID/128, NROW/128), 256, 0, stream>>>(
      Og, WoT, NHID, NHID, nullptr, nullptr, nullptr, nullptr, nullptr,
      nullptr, nullptr, nullptr, nullptr, out);
}

// Round 14
// 125.107 us; speedup vs baseline: 1.7576x; 1.0662x over previous
//
#include <hip/hip_runtime.h>
#include <hip/hip_bf16.h>

typedef short s16x4 __attribute__((ext_vector_type(4)));
typedef short s16x8 __attribute__((ext_vector_type(8)));
typedef float f32x4 __attribute__((ext_vector_type(4)));
typedef float f32x16 __attribute__((ext_vector_type(16)));

#define NB 2
#define NSEQ 2048
#define NHID 896
#define NHQ 14
#define NHKV 2
#define HD 64
#define NROW (NB*NSEQ)     // 4096
#define NCAT 2048          // 896 Q | 128 K | 128 V | 896 gate
#define PS 40              // padded LDS row stride in shorts (80B, 16B-aligned)
#define QSC 0.18033688011112042f   // (1/8) * log2(e), folded into Q at projection

__device__ __forceinline__ float bf2f(unsigned short s){
  union { float f; unsigned u; } v; v.u = ((unsigned)s) << 16; return v.f;
}
__device__ __forceinline__ short f2bf(float f){
  union { float f; unsigned u; } v; v.f = f;
  unsigned u = v.u + 0x7fffu + ((v.u >> 16) & 1u);
  return (short)(u >> 16);
}

// ---------------- packing kernels ----------------

__global__ void pack_x_kernel(const float* __restrict__ x, short* __restrict__ xb, int n){
  int i = blockIdx.x*256 + threadIdx.x;
  if(i < n) xb[i] = f2bf(x[i]);
}

// LDS-tiled transpose pack: WcatT[c][k] = W_region(k, c), coalesced both sides.
__global__ __launch_bounds__(256)
void pack_wcat_t_kernel(const float* __restrict__ Wq, const float* __restrict__ Wk,
                        const float* __restrict__ Wv, const float* __restrict__ Wg,
                        short* __restrict__ WcatT){
  __shared__ short T[64][73];
  int c0 = blockIdx.x*64, k0 = blockIdx.y*64;
  const float* src; int width, cb;
  if(c0 < 896){ src = Wq; width = 896; cb = c0; }
  else if(c0 < 1024){ src = Wk; width = 128; cb = c0-896; }
  else if(c0 < 1152){ src = Wv; width = 128; cb = c0-1024; }
  else { src = Wg; width = 896; cb = c0-1152; }
  int tid = threadIdx.x;
  #pragma unroll
  for(int it=0; it<4; ++it){
    int idx = it*256 + tid;           // 0..1023
    int r = idx >> 4, q = idx & 15;   // r = k-local, q = float4 chunk of c
    f32x4 v = *(const f32x4*)(src + (long)(k0+r)*width + cb + q*4);
    #pragma unroll
    for(int e=0;e<4;e++) T[r][q*4+e] = f2bf(v[e]);
  }
  __syncthreads();
  #pragma unroll
  for(int it=0; it<2; ++it){
    int idx = it*256 + tid;           // 0..511
    int c = idx >> 3, ch = idx & 7;
    s16x8 o;
    #pragma unroll
    for(int e=0;e<8;e++) o[e] = T[ch*8+e][c];
    *(s16x8*)(WcatT + (long)(c0+c)*NHID + k0 + ch*8) = o;
  }
}

__global__ __launch_bounds__(256)
void pack_wo_t_kernel(const float* __restrict__ Wo, short* __restrict__ WoT){
  __shared__ short T[64][73];
  int c0 = blockIdx.x*64, k0 = blockIdx.y*64;
  int tid = threadIdx.x;
  #pragma unroll
  for(int it=0; it<4; ++it){
    int idx = it*256 + tid;
    int r = idx >> 4, q = idx & 15;
    f32x4 v = *(const f32x4*)(Wo + (long)(k0+r)*896 + c0 + q*4);
    #pragma unroll
    for(int e=0;e<4;e++) T[r][q*4+e] = f2bf(v[e]);
  }
  __syncthreads();
  #pragma unroll
  for(int it=0; it<2; ++it){
    int idx = it*256 + tid;
    int c = idx >> 3, ch = idx & 7;
    s16x8 o;
    #pragma unroll
    for(int e=0;e<8;e++) o[e] = T[ch*8+e][c];
    *(s16x8*)(WoT + (long)(c0+c)*896 + k0 + ch*8) = o;
  }
}

__global__ void rope_table_kernel(const int* __restrict__ pos, float* __restrict__ ct,
                                  float* __restrict__ st){
  int t = blockIdx.x*256 + threadIdx.x;
  if(t >= NROW*32) return;
  int i = t & 31, rn = t >> 5;
  float p = (float)pos[rn];
  float inv = powf(1.0e6f, -(float)i * (1.0f/32.0f));
  float a = p * inv;
  ct[t] = cosf(a);
  st[t] = sinf(a);
}

// ---------------- K/V fragment packing ----------------
// Kp[bh][j][f=kt*4+ks][l] = K[bh][j*64+kt*32+(l&31)][16ks+8*(l>>5) .. +8)
// Vp[bh][j][f=mt*4+ss][l] : shorts[e]  = V[bh][j*64+16ss+4*(l>>5)+e  ][mt*32+(l&31)]
//                           shorts[4+e]= V[bh][j*64+16ss+4*(l>>5)+8+e][mt*32+(l&31)]

__global__ __launch_bounds__(256)
void pack_kv_kernel(const short* __restrict__ Kb, const short* __restrict__ Vb,
                    short* __restrict__ Kp, short* __restrict__ Vp){
  __shared__ short Kl[64][72];
  __shared__ short Vl[64][72];   // Vl[n][d]
  int j  = blockIdx.x;      // 0..31
  int bh = blockIdx.y;      // 0..3
  int tid = threadIdx.x;
  #pragma unroll
  for(int it=0; it<2; ++it){
    int idx = it*256 + tid;       // 0..511
    int r = idx >> 3, c0 = (idx & 7)*8;
    *(s16x8*)&Kl[r][c0] = *(const s16x8*)(Kb + ((long)bh*NSEQ + j*64 + r)*HD + c0);
    *(s16x8*)&Vl[r][c0] = *(const s16x8*)(Vb + ((long)bh*NSEQ + j*64 + r)*HD + c0);
  }
  __syncthreads();
  long base = ((long)bh*32 + j)*4096;
  #pragma unroll
  for(int it=0; it<2; ++it){
    int c = it*256 + tid;         // fragment-chunk 0..511
    int f = c >> 6, l = c & 63;
    int kt = f >> 2, ks = f & 3, h = l >> 5, r5 = l & 31;
    *(s16x8*)(Kp + base + f*512 + l*8) = *(const s16x8*)&Kl[kt*32 + r5][16*ks + 8*h];
    s16x8 o;
    #pragma unroll
    for(int e=0;e<4;e++){
      o[e]   = Vl[16*ks + 4*h + e    ][kt*32 + r5];
      o[4+e] = Vl[16*ks + 4*h + 8 + e][kt*32 + r5];
    }
    *(s16x8*)(Vp + base + f*512 + l*8) = o;
  }
}

// ---------------- GEMM (bf16 MFMA, reg-staged LDS double-buffer) ----------------
// EPI=0: QKVG epilogue (Q pre-scaled by QSC), EPI=1: plain f32 out
// XCD-aware block swizzle (grid size divisible by 8 for both uses: 512, 224).
// NOTE: every loop touching acc[][] MUST be #pragma unroll'd (rule #20).

template<int EPI>
__global__ __launch_bounds__(256)
void gemm_kernel(const short* __restrict__ A, const short* __restrict__ Bt,
                 int Ncols, int K,
                 const float* __restrict__ bq, const float* __restrict__ bk,
                 const float* __restrict__ bv,
                 const float* __restrict__ ct, const float* __restrict__ st,
                 short* __restrict__ Qb, short* __restrict__ Kb, short* __restrict__ Vb,
                 short* __restrict__ gateb, float* __restrict__ outp)
{
  __shared__ short As[2][128*PS];
  __shared__ short Bs[2][128*PS];

  int tid = threadIdx.x;
  int w = tid >> 6, l = tid & 63;
  int wm = w >> 1, wn = w & 1;

  // XCD swizzle: consecutive swizzled ids land on the same XCD.
  int bid = blockIdx.y * gridDim.x + blockIdx.x;
  int cpx = (gridDim.x * gridDim.y) >> 3;
  int swz = (bid & 7)*cpx + (bid >> 3);
  int bx = swz % gridDim.x, by = swz / gridDim.x;

  int row0 = by*128;
  int col0 = bx*128;
  int lo = l & 15, hi = l >> 4;

  const short* A0 = A  + (long)row0*K;
  const short* B0 = Bt + (long)col0*K;

  f32x4 acc[4][4];
  #pragma unroll
  for(int mi=0;mi<4;mi++)
    #pragma unroll
    for(int ni=0;ni<4;ni++) acc[mi][ni] = (f32x4){0.f,0.f,0.f,0.f};

  int srow = tid >> 2;
  int scol = (tid & 3)*8;

  s16x8 ra[2], rb[2];
  auto gload = [&](int k0){
    #pragma unroll
    for(int i=0;i<2;i++){
      int row = i*64 + srow;
      ra[i] = *(const s16x8*)(A0 + (long)row*K + k0 + scol);
      rb[i] = *(const s16x8*)(B0 + (long)row*K + k0 + scol);
    }
  };
  auto swrite = [&](int buf){
    #pragma unroll
    for(int i=0;i<2;i++){
      int row = i*64 + srow;
      *(s16x8*)&As[buf][row*PS + scol] = ra[i];
      *(s16x8*)&Bs[buf][row*PS + scol] = rb[i];
    }
  };

  gload(0);
  swrite(0);

  int NIT = K >> 5;
  int cur = 0;
  for(int it=0; it<NIT; ++it){
    __syncthreads();
    if(it+1 < NIT) gload((it+1)*32);

    s16x8 af[4], bf[4];
    #pragma unroll
    for(int mi=0;mi<4;mi++) af[mi] = *(const s16x8*)&As[cur][(wm*64 + 16*mi + lo)*PS + 8*hi];
    #pragma unroll
    for(int ni=0;ni<4;ni++) bf[ni] = *(const s16x8*)&Bs[cur][(wn*64 + 16*ni + lo)*PS + 8*hi];
    #pragma unroll
    for(int mi=0;mi<4;mi++)
      #pragma unroll
      for(int ni=0;ni<4;ni++)
        acc[mi][ni] = __builtin_amdgcn_mfma_f32_16x16x32_bf16(af[mi], bf[ni], acc[mi][ni], 0,0,0);

    if(it+1 < NIT) swrite(cur^1);
    cur ^= 1;
  }

  if(EPI == 1){
    #pragma unroll
    for(int mi=0;mi<4;mi++)
      #pragma unroll
      for(int ni=0;ni<4;ni++)
        #pragma unroll
        for(int rg=0;rg<4;rg++){
          int r = row0 + wm*64 + 16*mi + 4*hi + rg;
          int c = col0 + wn*64 + lo + 16*ni;
          outp[(long)r*Ncols + c] = acc[mi][ni][rg];
        }
  } else {
    int wcol0 = col0 + wn*64;
    int region = (wcol0 < 896) ? 0 : (wcol0 < 1024) ? 1 : (wcol0 < 1152) ? 2 : 3;
    #pragma unroll
    for(int mi=0;mi<4;mi++){
      #pragma unroll
      for(int rg=0;rg<4;rg++){
        int r = row0 + wm*64 + 16*mi + 4*hi + rg;
        int b = r >> 11, n = r & 2047;
        if(region <= 1){
          #pragma unroll
          for(int ni=0;ni<2;ni++){
            int c  = wcol0 + lo + 16*ni;
            int cb = (region==0) ? c : (c-896);
            int hh = cb >> 6, dlo = cb & 63;
            float bl = (region==0) ? bq[c]    : bk[cb];
            float bh = (region==0) ? bq[c+32] : bk[cb+32];
            float ylo = acc[mi][ni  ][rg] + bl;
            float yhi = acc[mi][ni+2][rg] + bh;
            float cs = ct[r*32 + dlo];
            float sn = st[r*32 + dlo];
            float olo = ylo*cs - yhi*sn;
            float ohi = yhi*cs + ylo*sn;
            if(region==0){
              long base = ((long)(b*NHQ + hh)*NSEQ + n)*HD;
              Qb[base + dlo]      = f2bf(olo*QSC);
              Qb[base + dlo + 32] = f2bf(ohi*QSC);
            } else {
              long base = ((long)(b*NHKV + hh)*NSEQ + n)*HD;
              Kb[base + dlo]      = f2bf(olo);
              Kb[base + dlo + 32] = f2bf(ohi);
            }
          }
        } else if(region == 2){
          #pragma unroll
          for(int ni=0;ni<4;ni++){
            int c = wcol0 + lo + 16*ni;
            int cv = c - 1024;
            int hh = cv >> 6, d = cv & 63;
            float y = acc[mi][ni][rg] + bv[cv];
            Vb[((long)(b*NHKV + hh)*NSEQ + n)*HD + d] = f2bf(y);
          }
        } else {
          #pragma unroll
          for(int ni=0;ni<4;ni++){
            int c = wcol0 + lo + 16*ni;
            int cg = c - 1152;
            float y = acc[mi][ni][rg];
            gateb[(long)r*NHID + cg] = f2bf(1.0f/(1.0f + __expf(-y)));
          }
        }
      }
    }
  }
}

// ---------------- split-K flash attention, 7 GQA heads per block ----------------
// Inner loop = EXACT R9-verified stream (passed R9/R11/R13). FROZEN — three
// restructures (R6/R10/R12) all failed. This round changes ONLY the chunk->
// slot map (outside the loop): 120 slots/kvb = 480 blocks <= 512 resident
// (2 blocks/CU at 88 VGPR x 7 waves) -> ONE dispatch round, even chunk sizes
// (<=12 steps). t<24: 1 chunk; t 24..47: 2 even halves; t 48..63: 3 thirds.

__global__ __launch_bounds__(448)
void attn3_kernel(const short* __restrict__ Qb, const short* __restrict__ Kp,
                  const short* __restrict__ Vp, const short* __restrict__ gateb,
                  short* __restrict__ Og, float* __restrict__ Pbuf)
{
  int tid = threadIdx.x;
  int l = tid & 63;
  int q5 = l & 31, h = l >> 5;
  int hg = tid >> 6;              // wave id = head-in-group 0..6

  int s = 119 - blockIdx.x;       // LPT-ish: multi-chunk slots first
  int kvb = blockIdx.y;           // 0..3 = (b,kv)
  int b = kvb >> 1, kv = kvb & 1;
  int hq = kv*7 + hg;
  int head = kvb*7 + hg;          // Pbuf head index (matches combine decode)

  int t, ci, nc;
  if(s < 24){ t = s; ci = 0; nc = 1; }
  else if(s < 72){ int r = s-24; t = 24 + (r>>1); ci = r & 1; nc = 2; }
  else { int r = s-72; t = 48 + r/3; ci = r - (r/3)*3; nc = 3; }

  int qg = t*32 + q5;
  int jcausal = (t*32 + 31) >> 6;           // diagonal 64-key group; in last chunk
  int ng = jcausal + 1;
  int j0, j1;
  if(nc == 1){ j0 = 0; j1 = jcausal; }
  else if(nc == 2){
    int half = (ng + 1) >> 1;
    j0 = ci ? half : 0;
    j1 = ci ? jcausal : (half - 1);
  } else {
    int third = (ng + 2) / 3;
    j0 = ci * third;
    j1 = (ci == 2) ? jcausal : (j0 + third - 1);
  }

  const short* qrow = Qb + ((long)(b*NHQ + hq)*NSEQ + t*32 + q5)*HD;
  s16x8 qf[4];
  #pragma unroll
  for(int ks=0; ks<4; ++ks) qf[ks] = *(const s16x8*)(qrow + 16*ks + 8*h);

  const short* kpb = Kp + (long)kvb*32*4096 + l*8;
  const short* vpb = Vp + (long)kvb*32*4096 + l*8;

  f32x16 oT[2];
  #pragma unroll
  for(int mt=0; mt<2; ++mt)
    #pragma unroll
    for(int rg=0; rg<16; ++rg) oT[mt][rg] = 0.f;
  float m = -__builtin_inff(), lsum = 0.f;

  // preload K group j0 (coalesced fragment reads)
  s16x8 kf[2][4];
  #pragma unroll
  for(int kt=0; kt<2; ++kt)
    #pragma unroll
    for(int ks=0; ks<4; ++ks)
      kf[kt][ks] = *(const s16x8*)(kpb + (long)j0*4096 + (kt*4+ks)*512);

  for(int j=j0; j<=j1; ++j){
    // V fragments (coalesced)
    s16x8 vf[2][4];
    #pragma unroll
    for(int mt=0; mt<2; ++mt)
      #pragma unroll
      for(int ss=0; ss<4; ++ss)
        vf[mt][ss] = *(const s16x8*)(vpb + (long)j*4096 + (mt*4+ss)*512);

    // S^T = K * Q^T (softmax scale pre-folded into Q, log2 domain)
    f32x16 s2[2];
    #pragma unroll
    for(int kt=0; kt<2; ++kt)
      #pragma unroll
      for(int rg=0; rg<16; ++rg) s2[kt][rg] = 0.f;
    #pragma unroll
    for(int kt=0; kt<2; ++kt)
      #pragma unroll
      for(int ks=0; ks<4; ++ks)
        s2[kt] = __builtin_amdgcn_mfma_f32_32x32x16_bf16(kf[kt][ks], qf[ks], s2[kt], 0,0,0);

    // prefetch next K group while softmax+PV run
    int jn = (j < j1) ? j+1 : j;
    s16x8 kn[2][4];
    #pragma unroll
    for(int kt=0; kt<2; ++kt)
      #pragma unroll
      for(int ks=0; ks<4; ++ks)
        kn[kt][ks] = *(const s16x8*)(kpb + (long)jn*4096 + (kt*4+ks)*512);

    // causal mask (diagonal group only). key row = (rg&3)+8*(rg>>2)+4h
    if(j == jcausal){
      #pragma unroll
      for(int kt=0; kt<2; ++kt)
        #pragma unroll
        for(int rg=0; rg<16; ++rg){
          int kl = j*64 + kt*32 + (rg&3) + 8*(rg>>2) + 4*h;
          if(kl > qg) s2[kt][rg] = -__builtin_inff();
        }
    }

    // row-max: in-lane tree + 1 shuffle across h
    float mA[8];
    #pragma unroll
    for(int w8=0; w8<8; ++w8)
      mA[w8] = fmaxf(fmaxf(s2[0][w8], s2[0][w8+8]), fmaxf(s2[1][w8], s2[1][w8+8]));
    float mx = fmaxf(fmaxf(fmaxf(mA[0],mA[1]), fmaxf(mA[2],mA[3])),
                     fmaxf(fmaxf(mA[4],mA[5]), fmaxf(mA[6],mA[7])));
    mx = fmaxf(mx, __shfl_xor(mx, 32, 64));

    // defer-max: only rescale when max grew by > 8 (log2 domain, P <= 256)
    if(__any(mx > m + 8.0f)){
      float mn = fmaxf(m, mx);
      float fac = exp2f(m - mn);
      m = mn;
      lsum *= fac;
      #pragma unroll
      for(int mt=0; mt<2; ++mt)
        #pragma unroll
        for(int rg=0; rg<16; ++rg) oT[mt][rg] *= fac;
    }

    // exp + row-sum (tree + 1 shuffle)
    #pragma unroll
    for(int kt=0; kt<2; ++kt)
      #pragma unroll
      for(int rg=0; rg<16; ++rg) s2[kt][rg] = exp2f(s2[kt][rg] - m);
    float sA[8];
    #pragma unroll
    for(int w8=0; w8<8; ++w8)
      sA[w8] = (s2[0][w8] + s2[0][w8+8]) + (s2[1][w8] + s2[1][w8+8]);
    float rs = ((sA[0]+sA[1]) + (sA[2]+sA[3])) + ((sA[4]+sA[5]) + (sA[6]+sA[7]));
    rs += __shfl_xor(rs, 32, 64);
    lsum += rs;

    // pack P to bf16 pairs: pd[kt][w] = {p[2w] lo, p[2w+1] hi}
    int pd[2][8];
    #pragma unroll
    for(int kt=0; kt<2; ++kt)
      #pragma unroll
      for(int w8=0; w8<8; ++w8)
        asm("v_cvt_pk_bf16_f32 %0, %1, %2"
            : "=v"(pd[kt][w8]) : "v"(s2[kt][2*w8]), "v"(s2[kt][2*w8+1]));

    // PV: O^T += V^T * P^T ; B-frag for step ss = pd[ss>>1][4*(ss&1) .. +3]
    #pragma unroll
    for(int ss=0; ss<4; ++ss){
      union { int i4[4]; s16x8 v8; } pf;
      #pragma unroll
      for(int e=0; e<4; ++e) pf.i4[e] = pd[ss>>1][4*(ss&1) + e];
      #pragma unroll
      for(int mt=0; mt<2; ++mt)
        oT[mt] = __builtin_amdgcn_mfma_f32_32x32x16_bf16(vf[mt][ss], pf.v8, oT[mt], 0,0,0);
    }

    // roll K prefetch
    #pragma unroll
    for(int kt=0; kt<2; ++kt)
      #pragma unroll
      for(int ks=0; ks<4; ++ks) kf[kt][ks] = kn[kt][ks];
  }

  if(nc == 1){
    float inv = 1.0f/lsum;
    long obase = ((long)(b*NSEQ + t*32 + q5))*NHID + hq*HD;
    #pragma unroll
    for(int mt=0; mt<2; ++mt)
      #pragma unroll
      for(int rq=0; rq<4; ++rq){
        int d0 = mt*32 + 8*rq + 4*h;
        s16x4 g4 = *(const s16x4*)(gateb + obase + d0);
        s16x4 o4;
        #pragma unroll
        for(int e=0; e<4; ++e)
          o4[e] = f2bf(oT[mt][4*rq + e]*inv*bf2f((unsigned short)g4[e]));
        *(s16x4*)(Og + obase + d0) = o4;
      }
  } else {
    int poff = (nc == 2) ? (t-24)*2 : 48 + (t-48)*3;
    float* pb = Pbuf + ((long)head*144 + poff + ci)*2112;
    #pragma unroll
    for(int mt=0; mt<2; ++mt)
      #pragma unroll
      for(int rg=0; rg<16; ++rg){
        int d = mt*32 + (rg&3) + 8*(rg>>2) + 4*h;
        pb[q5*64 + d] = oT[mt][rg];
      }
    if(h == 0){
      pb[2048 + q5] = m;
      pb[2080 + q5] = lsum;
    }
  }
}

// ---------------- split-K combine (t >= 24 tiles) ----------------

__global__ __launch_bounds__(64)
void attn_combine_kernel(const float* __restrict__ Pbuf, const short* __restrict__ gateb,
                         short* __restrict__ Og)
{
  int t = 24 + blockIdx.x;        // 24..63
  int head = blockIdx.y;          // 0..27
  int hg = head % 7; int kvb = head / 7; int b = kvb >> 1; int kv = kvb & 1;
  int hq = kv*7 + hg;
  int nc = (t < 48) ? 2 : 3;
  int poff = (t < 48) ? (t-24)*2 : 48 + (t-48)*3;
  const float* pb0 = Pbuf + ((long)head*144 + poff)*2112;

  int l = threadIdx.x;
  int q5 = l & 31;
  int d0 = (l >> 5)*32;

  float ms[3];
  float M = -__builtin_inff();
  #pragma unroll
  for(int i=0;i<3;i++){
    ms[i] = (i < nc) ? pb0[i*2112 + 2048 + q5] : -__builtin_inff();
    M = fmaxf(M, ms[i]);
  }
  float L = 0.f;
  f32x4 Oa[8];
  #pragma unroll
  for(int c=0;c<8;c++) Oa[c] = (f32x4){0.f,0.f,0.f,0.f};
  #pragma unroll
  for(int i=0;i<3;i++){
    if(i < nc){
      float fac = exp2f(ms[i] - M);
      L += pb0[i*2112 + 2080 + q5] * fac;
      const float* po = pb0 + i*2112 + q5*64 + d0;
      #pragma unroll
      for(int c=0;c<8;c++){
        f32x4 v = *(const f32x4*)(po + 4*c);
        #pragma unroll
        for(int e=0;e<4;e++) Oa[c][e] += v[e]*fac;
      }
    }
  }
  float inv = 1.0f/L;
  long obase = ((long)(b*NSEQ + t*32 + q5))*NHID + hq*HD + d0;
  #pragma unroll
  for(int c=0;c<8;c++){
    s16x4 g4 = *(const s16x4*)(gateb + obase + 4*c);
    s16x4 o4;
    #pragma unroll
    for(int e=0;e<4;e++)
      o4[e] = f2bf(Oa[c][e]*inv*bf2f((unsigned short)g4[e]));
    *(s16x4*)(Og + obase + 4*c) = o4;
  }
}

// ---------------- launch ----------------

extern "C" void kernel_launch(void* const* d_in, const int* in_sizes, int n_in,
                              void* d_out, int out_size, void* d_ws, size_t ws_size,
                              hipStream_t stream)
{
  const float* hs  = (const float*)d_in[0];
  const int*   pos = (const int*)d_in[1];
  const float* Wq  = (const float*)d_in[2];
  const float* bq  = (const float*)d_in[3];
  const float* Wk  = (const float*)d_in[4];
  const float* bk  = (const float*)d_in[5];
  const float* Wv  = (const float*)d_in[6];
  const float* bv  = (const float*)d_in[7];
  const float* Wg  = (const float*)d_in[8];
  const float* Wo  = (const float*)d_in[9];
  float* out = (float*)d_out;

  char* p = (char*)d_ws;
  short* Xb    = (short*)p; p += (size_t)NROW*NHID*2;
  short* WcatT = (short*)p; p += (size_t)NCAT*NHID*2;
  short* WoT   = (short*)p; p += (size_t)NHID*NHID*2;
  float* ct    = (float*)p; p += (size_t)NROW*32*4;
  float* st    = (float*)p; p += (size_t)NROW*32*4;
  short* Qb    = (short*)p; p += (size_t)NB*NHQ*NSEQ*HD*2;
  short* Kb    = (short*)p; p += (size_t)NB*NHKV*NSEQ*HD*2;
  short* Vb    = (short*)p; p += (size_t)NB*NHKV*NSEQ*HD*2;
  short* Kp    = (short*)p; p += (size_t)4*32*4096*2;     // packed K fragments (1 MB)
  short* Vp    = (short*)p; p += (size_t)4*32*4096*2;     // packed V fragments (1 MB)
  short* gateb = (short*)p; p += (size_t)NROW*NHID*2;
  short* Og    = (short*)p; p += (size_t)NROW*NHID*2;
  float* Pbuf  = (float*)p; p += (size_t)28*144*2112*4;   // split-K partials (96/144 used)

  pack_x_kernel<<<(NROW*NHID+255)/256, 256, 0, stream>>>(hs, Xb, NROW*NHID);
  pack_wcat_t_kernel<<<dim3(NCAT/64, NHID/64), 256, 0, stream>>>(Wq, Wk, Wv, Wg, WcatT);
  pack_wo_t_kernel<<<dim3(NHID/64, NHID/64), 256, 0, stream>>>(Wo, WoT);
  rope_table_kernel<<<(NROW*32+255)/256, 256, 0, stream>>>(pos, ct, st);

  gemm_kernel<0><<<dim3(NCAT/128, NROW/128), 256, 0, stream>>>(
      Xb, WcatT, NCAT, NHID, bq, bk, bv, ct, st, Qb, Kb, Vb, gateb, nullptr);

  pack_kv_kernel<<<dim3(32, 4), 256, 0, stream>>>(Kb, Vb, Kp, Vp);

  attn3_kernel<<<dim3(120, 4), 448, 0, stream>>>(Qb, Kp, Vp, gateb, Og, Pbuf);
  attn_combine_kernel<<<dim3(40, 28), 64, 0, stream>>>(Pbuf, gateb, Og);

  gemm_kernel<1><<<dim3(NHID/128, NROW/128), 256, 0, stream>>>(
      Og, WoT, NHID, NHID, nullptr, nullptr, nullptr, nullptr, nullptr,
      nullptr, nullptr, nullptr, nullptr, out);
}